// Round 5
// baseline (590.487 us; speedup 1.0000x reference)
//
#include <hip/hip_runtime.h>
#include <hip/hip_bf16.h>
#include <math.h>

// ExpertChoiceMoELayer: B=8,S=2048,D=1024,F=2048,E=8 -> T=16384, cap=2048
#define T_TOK 16384
#define DIM   1024
#define FF    2048
#define NE    8
#define CAPK  2048
#define MTE_MAX 16
#define WL1SZ (NE * 8 * MTE_MAX)  // 1024
#define WL2SZ (NE * 4 * MTE_MAX)  // 512

typedef unsigned short u16;
typedef unsigned long long u64;
typedef __attribute__((ext_vector_type(8))) short bf16x8;
typedef __attribute__((ext_vector_type(4))) float f32x4;

__device__ __forceinline__ u16 f2bf(float f) {
  __hip_bfloat16 h = __float2bfloat16(f);
  union { __hip_bfloat16 h; u16 u; } c; c.h = h; return c.u;
}

// fast GELU: 0.5x(1+erf(x/sqrt2)), erf via Abramowitz-Stegun 7.1.26 (|err|<=1.5e-7)
__device__ __forceinline__ float gelu_f(float v) {
  float z = fabsf(v) * 0.70710678118654752f;
  float t = __builtin_amdgcn_rcpf(1.0f + 0.3275911f * z);
  float poly = t * (0.254829592f +
               t * (-0.284496736f +
               t * (1.421413741f +
               t * (-1.453152027f +
               t * 1.061405429f))));
  float ez = __expf(-z * z);
  float erfz = 1.0f - poly * ez;
  erfz = copysignf(erfz, v);
  return 0.5f * v * (1.0f + erfz);
}

__device__ __forceinline__ void async_copy16(const void* g, void* l) {
  __builtin_amdgcn_global_load_lds(
      (const __attribute__((address_space(1))) unsigned int*)g,
      (__attribute__((address_space(3))) unsigned int*)l, 16, 0, 0);
}

// ---- fp32 [E][R][C] -> bf16 [E][C][R] ----
__global__ __launch_bounds__(256) void transpose_cvt(const float* __restrict__ src,
                                                     u16* __restrict__ dst, int R, int C) {
  __shared__ float tile[32][35];
  int e = blockIdx.z;
  int c0 = blockIdx.x * 32, r0 = blockIdx.y * 32;
  const float* s = src + (size_t)e * R * C;
  u16* d = dst + (size_t)e * R * C;
  int tid = threadIdx.x;
#pragma unroll
  for (int i = 0; i < 4; ++i) {
    int idx = tid + i * 256;
    int r = idx >> 5, c = idx & 31;
    tile[r][c] = s[(size_t)(r0 + r) * C + c0 + c];
  }
  __syncthreads();
  int q = tid & 7, cc = tid >> 3;
  ushort4 h;
  h.x = f2bf(tile[q * 4 + 0][cc]);
  h.y = f2bf(tile[q * 4 + 1][cc]);
  h.z = f2bf(tile[q * 4 + 2][cc]);
  h.w = f2bf(tile[q * 4 + 3][cc]);
  *(ushort4*)(d + (size_t)(c0 + cc) * R + r0 + q * 4) = h;
}

// ---- router: fp64-accum logits + softmax; probs [T][E], probsT [E][T], xb bf16;
//      also clears key/cnt/cnt2 (fused init) ----
__global__ __launch_bounds__(256) void router_k(const float* __restrict__ x,
                                                const float* __restrict__ Wg,
                                                float* __restrict__ probs,
                                                float* __restrict__ probsT,
                                                u16* __restrict__ xb,
                                                u64* __restrict__ key,
                                                int* cnt, int* cnt2) {
  int tid = threadIdx.x;
  if (tid < 4) key[blockIdx.x * 4 + tid] = 0ull;
  if (blockIdx.x == 0 && tid < NE) { cnt[tid] = 0; cnt2[tid] = 0; }
  int wid = tid >> 6, lane = tid & 63;
  int t = blockIdx.x * 4 + wid;
  const float* xr = x + (size_t)t * DIM;
  u16* xbr = xb + (size_t)t * DIM;
  double acc[NE] = {0, 0, 0, 0, 0, 0, 0, 0};
#pragma unroll 1
  for (int it = 0; it < DIM / 64; ++it) {
    int d = it * 64 + lane;
    float xv = xr[d];
    xbr[d] = f2bf(xv);
    const float4* wrow = (const float4*)(Wg + (size_t)d * NE);
    float4 w0 = wrow[0], w1 = wrow[1];
    acc[0] += (double)xv * (double)w0.x;
    acc[1] += (double)xv * (double)w0.y;
    acc[2] += (double)xv * (double)w0.z;
    acc[3] += (double)xv * (double)w0.w;
    acc[4] += (double)xv * (double)w1.x;
    acc[5] += (double)xv * (double)w1.y;
    acc[6] += (double)xv * (double)w1.z;
    acc[7] += (double)xv * (double)w1.w;
  }
#pragma unroll
  for (int e = 0; e < NE; ++e)
    for (int o = 32; o > 0; o >>= 1) acc[e] += __shfl_down(acc[e], o, 64);
  if (lane == 0) {
    float l[NE], mx = -3.0e38f;
#pragma unroll
    for (int e = 0; e < NE; ++e) { l[e] = (float)acc[e]; mx = fmaxf(mx, l[e]); }
    float s = 0.f;
#pragma unroll
    for (int e = 0; e < NE; ++e) { l[e] = expf(l[e] - mx); s += l[e]; }
    float inv = 1.0f / s;
#pragma unroll
    for (int e = 0; e < NE; ++e) {
      float p = l[e] * inv;
      probs[(size_t)t * NE + e] = p;
      probsT[(size_t)e * T_TOK + t] = p;
    }
  }
}

// ---- per-expert exact top-CAPK: 3-level radix (11/11/10 bits), per-wave L0 hist ----
__global__ __launch_bounds__(256) void topk_sel(const float* __restrict__ probsT,
                                                u64* __restrict__ key) {
  __shared__ float pcol[T_TOK];          // 64 KB
  __shared__ unsigned whist[8][2048];    // 64 KB (level-0 per-wave)
  __shared__ unsigned hist[2048];        // 8 KB
  __shared__ unsigned chunk[256];
  __shared__ unsigned bcast[2];
  __shared__ int tcnt[256];
  int e = blockIdx.x, tid = threadIdx.x, wid = tid >> 6;
  const float4* src4 = (const float4*)(probsT + (size_t)e * T_TOK);
  for (int i = tid; i < T_TOK / 4; i += 256) ((float4*)pcol)[i] = src4[i];
  for (int i = tid; i < 8 * 2048; i += 256) ((unsigned*)whist)[i] = 0;
  unsigned prefix = 0, remaining = CAPK;
#pragma unroll 1
  for (int lvl = 0; lvl < 3; ++lvl) {
    int nb = (lvl == 2) ? 1024 : 2048;
    if (lvl == 0) {
      __syncthreads();
      for (int i = tid; i < T_TOK; i += 256)
        atomicAdd(&whist[wid][__float_as_uint(pcol[i]) >> 21], 1u);
      __syncthreads();
      for (int j = tid; j < 2048; j += 256) {
        unsigned s = 0;
#pragma unroll
        for (int w = 0; w < 8; ++w) s += whist[w][j];
        hist[j] = s;
      }
      __syncthreads();
    } else {
      for (int i = tid; i < 2048; i += 256) hist[i] = 0;
      __syncthreads();
      for (int i = tid; i < T_TOK; i += 256) {
        unsigned k = __float_as_uint(pcol[i]);
        bool m = (lvl == 1) ? ((k >> 21) == prefix) : ((k >> 10) == prefix);
        if (m) atomicAdd(&hist[(lvl == 1) ? ((k >> 10) & 2047u) : (k & 1023u)], 1u);
      }
      __syncthreads();
    }
    int nper = nb / 256;
    unsigned s = 0;
    for (int j = nper - 1; j >= 0; --j) s += hist[tid * nper + j];
    chunk[tid] = s;
    __syncthreads();
    if (tid == 0) {
      unsigned cum = 0;
      int ct = 0;
      for (int t2 = 255; t2 >= 0; --t2) {
        if (cum + chunk[t2] >= remaining) { ct = t2; break; }
        cum += chunk[t2];
      }
      unsigned rem2 = remaining - cum, cum2 = 0;
      for (int j = nper - 1; j >= 0; --j) {
        unsigned h = hist[ct * nper + j];
        if (cum2 + h >= rem2) {
          bcast[0] = (unsigned)(ct * nper + j);
          bcast[1] = rem2 - cum2;
          break;
        }
        cum2 += h;
      }
    }
    __syncthreads();
    unsigned b = bcast[0];
    remaining = bcast[1];
    prefix = (lvl == 0) ? b : (lvl == 1) ? ((prefix << 11) | b) : ((prefix << 10) | b);
    __syncthreads();
  }
  unsigned vk = prefix;
  int need = (int)remaining;
  const int CH = T_TOK / 256;
  int i0 = tid * CH;
  int myt = 0;
  for (int i = i0; i < i0 + CH; ++i)
    myt += (__float_as_uint(pcol[i]) == vk);
  tcnt[tid] = myt;
  __syncthreads();
  if (tid == 0) {
    int r = 0;
    for (int j = 0; j < 256; ++j) { int v = tcnt[j]; tcnt[j] = r; r += v; }
  }
  __syncthreads();
  int run = tcnt[tid];
  u64 ebits = (u64)(7 - e);
  for (int i = i0; i < i0 + CH; ++i) {
    unsigned k = __float_as_uint(pcol[i]);
    bool sv = false;
    if (k > vk) sv = true;
    else if (k == vk) { if (run < need) sv = true; run++; }
    if (sv) atomicMax(&key[i], ((u64)k << 3) | ebits);
  }
}

__global__ __launch_bounds__(256) void assign_k(const float* __restrict__ probs,
                                                const u64* __restrict__ key,
                                                int* __restrict__ tok2exp,
                                                float* __restrict__ wgt, int* cnt) {
  int t = blockIdx.x * 256 + threadIdx.x;
  u64 k = key[t];
  int best;
  float bp;
  if (k) {
    best = 7 - (int)(k & 7);
    bp = __uint_as_float((unsigned)(k >> 3));
  } else {
    best = 0; bp = -3.0e38f;
#pragma unroll
    for (int e = 0; e < NE; ++e) {
      float p = probs[(size_t)t * NE + e];
      if (p > bp) { bp = p; best = e; }
    }
  }
  tok2exp[t] = best;
  wgt[t] = bp;
  atomicAdd(&cnt[best], 1);
}

// basep + XCD-local worklists: entry w -> expert w%8 (block w -> XCD w%8)
__global__ __launch_bounds__(256) void wl_build(const int* __restrict__ cnt,
                                                int* basep, int* wl1, int* wl2) {
  int gid = blockIdx.x * 256 + threadIdx.x;
  int c[NE];
#pragma unroll
  for (int e = 0; e < NE; ++e) c[e] = cnt[e];
  if (gid < NE) {
    int r = 0;
    for (int e = 0; e < gid; ++e) r += c[e];
    basep[gid] = r;
  }
  if (gid < WL1SZ) {
    int e = gid & 7, j = gid >> 3;
    int mte = (c[e] + 255) >> 8;
    int v = -1;
    if (j < 8 * mte) {       // nt half-split: WS = A-panel + 4 B-panels < L2
      int half = 4 * mte;
      int h = (j >= half) ? 1 : 0;
      int jj = j - h * half;
      v = e | ((jj >> 2) << 4) | (((h << 2) | (jj & 3)) << 12);
    }
    wl1[gid] = v;
  }
  int g2 = gid - WL1SZ;
  if (g2 >= 0 && g2 < WL2SZ) {
    int e = g2 & 7, j = g2 >> 3;
    int mte = (c[e] + 255) >> 8;
    int v = -1;
    if (j < 4 * mte) {
      int half = 2 * mte;
      int h = (j >= half) ? 1 : 0;
      int jj = j - h * half;
      v = e | ((jj >> 1) << 4) | (((h << 1) | (jj & 1)) << 12);
    }
    wl2[g2] = v;
  }
}

__global__ __launch_bounds__(256) void slot_k(const int* __restrict__ tok2exp,
                                              const int* __restrict__ basep,
                                              int* cnt2, int* __restrict__ list) {
  int t = blockIdx.x * 256 + threadIdx.x;
  int e = tok2exp[t];
  int s = basep[e] + atomicAdd(&cnt2[e], 1);
  list[s] = t;
}

// ============ deep-pipelined grouped GEMM: 256x256 tile, BK=32, 4-slot ring, ============
// stage 3 K-tiles ahead, counted vmcnt (8/4/0), swizzled LDS, setprio, op-swapped MFMA
// EPI=0: H[slot] = GELU(xb[tok] @ W1t^T)   (K=DIM, N=FF) ; A gathered via toks
// EPI=1: out[tok] = wgt * (H[slot] @ W2t^T) (K=FF,  N=DIM) ; A dense by slot

#define MF(M, N_, AV, BV) acc[M][N_] = __builtin_amdgcn_mfma_f32_16x16x32_bf16(BV, AV, acc[M][N_], 0, 0, 0)

#define SLOT_A(s) (sm + (s) * 32768)
#define SLOT_B(s) (sm + (s) * 32768 + 16384)

#define PHASE_DSA(s, mh)                                                          \
  pa = SLOT_A(s) + wr * 8192 + (mh) * 4096 + laneOff;                             \
  a0 = *(const bf16x8*)(pa);                                                      \
  a1 = *(const bf16x8*)(pa + 1024);                                               \
  a2 = *(const bf16x8*)(pa + 2048);                                               \
  a3 = *(const bf16x8*)(pa + 3072);

#define PHASE_DSB(s)                                                              \
  pb = SLOT_B(s) + wc * 4096 + laneOff;                                           \
  b0 = *(const bf16x8*)(pb);                                                      \
  b1 = *(const bf16x8*)(pb + 1024);                                               \
  b2 = *(const bf16x8*)(pb + 2048);                                               \
  b3 = *(const bf16x8*)(pb + 3072);

#define PHASE_MFMA(mh)                                                            \
  do {                                                                            \
    __builtin_amdgcn_s_setprio(1);                                                \
    MF((mh) * 4 + 0, 0, a0, b0); MF((mh) * 4 + 0, 1, a0, b1);                     \
    MF((mh) * 4 + 0, 2, a0, b2); MF((mh) * 4 + 0, 3, a0, b3);                     \
    MF((mh) * 4 + 1, 0, a1, b0); MF((mh) * 4 + 1, 1, a1, b1);                     \
    MF((mh) * 4 + 1, 2, a1, b2); MF((mh) * 4 + 1, 3, a1, b3);                     \
    MF((mh) * 4 + 2, 0, a2, b0); MF((mh) * 4 + 2, 1, a2, b1);                     \
    MF((mh) * 4 + 2, 2, a2, b2); MF((mh) * 4 + 2, 3, a2, b3);                     \
    MF((mh) * 4 + 3, 0, a3, b0); MF((mh) * 4 + 3, 1, a3, b1);                     \
    MF((mh) * 4 + 3, 2, a3, b2); MF((mh) * 4 + 3, 3, a3, b3);                     \
    __builtin_amdgcn_s_setprio(0);                                                \
  } while (0)

#define STAGE_A(s, kt)                                                            \
  do {                                                                            \
    async_copy16(aP0 + (size_t)(kt) * 64, SLOT_A(s) + wid * 1024);                \
    async_copy16(aP1 + (size_t)(kt) * 64, SLOT_A(s) + 8192 + wid * 1024);         \
  } while (0)

#define STAGE_B(s, kt)                                                            \
  do {                                                                            \
    async_copy16(bP0 + (size_t)(kt) * 64, SLOT_B(s) + wid * 1024);                \
    async_copy16(bP1 + (size_t)(kt) * 64, SLOT_B(s) + 8192 + wid * 1024);         \
  } while (0)

#define BAR() asm volatile("s_barrier" ::: "memory")

template <int EPI>
__global__ __launch_bounds__(512, 2) void ffn_k(const u16* __restrict__ A,
                                                const u16* __restrict__ Bm,
                                                void* __restrict__ Out,
                                                const int* __restrict__ list,
                                                const float* __restrict__ wgt,
                                                const int* __restrict__ basep,
                                                const int* __restrict__ cnt,
                                                const int* __restrict__ wl) {
  constexpr int K = EPI ? FF : DIM;
  constexpr int N = EPI ? DIM : FF;
  constexpr int KT = K / 32;

  const int wle = wl[blockIdx.x];
  if (wle < 0) return;
  const int e = wle & 15, mt = (wle >> 4) & 255, nt = wle >> 12;
  const int ce = cnt[e];
  const int be = basep[e];

  __shared__ u16 smem[65536];   // 128 KiB: 4 ring slots x (A 16KB + B 16KB)
  __shared__ int toks[256];
  __shared__ float wsc[256];
  char* const sm = (char*)smem;

  const int tid = threadIdx.x;
  if (tid < 256) {
    int r = mt * 256 + tid;
    int tk = (r < ce) ? list[be + r] : list[be];
    toks[tid] = tk;
    if (EPI == 1) wsc[tid] = wgt[tk];
  }
  __syncthreads();

  const int wid = tid >> 6, lane = tid & 63;
  const int wr = wid >> 2, wc = wid & 3;
  // swizzled per-lane frag-read offset (2 rows per 128B line, XOR on line&3)
  const int laneOff = ((lane & 15) >> 1) * 128 + (lane & 1) * 64 +
                      (((lane >> 4) << 4) ^ (((lane >> 1) & 3) << 4));

  // staging: thread covers tile rows tr0 (call 0) and tr1=tr0+128 (call 1)
  const int tr0 = ((tid >> 3) << 1) + ((tid >> 2) & 1), tr1 = 128 + tr0;
  const int cbl = ((tid & 3) << 4) ^ (((tid >> 3) & 3) << 4);
  const char *aP0, *aP1;
  if (EPI == 0) {
    aP0 = (const char*)(A + (size_t)toks[tr0] * K) + cbl;
    aP1 = (const char*)(A + (size_t)toks[tr1] * K) + cbl;
  } else {
    aP0 = (const char*)(A + ((size_t)be + mt * 256 + tr0) * K) + cbl;
    aP1 = (const char*)(A + ((size_t)be + mt * 256 + tr1) * K) + cbl;
  }
  const char* bP0 = (const char*)(Bm + ((size_t)e * N + nt * 256 + tr0) * K) + cbl;
  const char* bP1 = (const char*)(Bm + ((size_t)e * N + nt * 256 + tr1) * K) + cbl;

  f32x4 acc[8][4];
#pragma unroll
  for (int m = 0; m < 8; ++m)
#pragma unroll
    for (int n = 0; n < 4; ++n) acc[m][n] = (f32x4){0.f, 0.f, 0.f, 0.f};

  // prologue: stage slots 0,1,2 (3 K-tiles ahead)
  STAGE_A(0, 0); STAGE_B(0, 0);
  STAGE_A(1, 1); STAGE_B(1, 1);
  STAGE_A(2, 2); STAGE_B(2, 2);
  asm volatile("s_waitcnt vmcnt(8)" ::: "memory");  // slot 0 complete
  BAR();

  const char* pa;
  const char* pb;
  bf16x8 a0, a1, a2, a3, b0, b1, b2, b3;

#pragma unroll 1
  for (int kt = 0; kt < KT; ++kt) {
    const int s = kt & 3, sn = (kt + 3) & 3;
    const bool pf = (kt + 3 < KT);
    // P1: issue A-prefetch early; read mh0 frags + B frags; barrier; MFMA
    if (pf) STAGE_A(sn, kt + 3);
    PHASE_DSA(s, 0);
    PHASE_DSB(s);
    BAR();
    PHASE_MFMA(0);
    // P2: issue B-prefetch; read mh1 frags; counted vmcnt -> slot kt+1 ready
    if (pf) STAGE_B(sn, kt + 3);
    PHASE_DSA(s, 1);
    if (kt < KT - 3)       asm volatile("s_waitcnt vmcnt(8)" ::: "memory");
    else if (kt == KT - 3) asm volatile("s_waitcnt vmcnt(4)" ::: "memory");
    else                   asm volatile("s_waitcnt vmcnt(0)" ::: "memory");
    BAR();
    PHASE_MFMA(1);
    BAR();   // closes WAR: slot s fully read before iteration kt+1 stages into it
  }

  // epilogue: operand-swap => acc reg index runs along output cols -> vector stores
  const int lc = lane & 15, lq = (lane >> 4) * 4;
#pragma unroll
  for (int m = 0; m < 8; ++m) {
    int trow = wr * 128 + m * 16 + lc;
    int grow = mt * 256 + trow;
    if (grow < ce) {
      if (EPI == 0) {
        size_t rowoff = (size_t)(be + grow) * FF + nt * 256 + wc * 64 + lq;
#pragma unroll
        for (int n = 0; n < 4; ++n) {
          ushort4 h4;
          h4.x = f2bf(gelu_f(acc[m][n][0]));
          h4.y = f2bf(gelu_f(acc[m][n][1]));
          h4.z = f2bf(gelu_f(acc[m][n][2]));
          h4.w = f2bf(gelu_f(acc[m][n][3]));
          *(ushort4*)((u16*)Out + rowoff + n * 16) = h4;
        }
      } else {
        float w = wsc[trow];
        size_t rowoff = (size_t)toks[trow] * DIM + nt * 256 + wc * 64 + lq;
#pragma unroll
        for (int n = 0; n < 4; ++n) {
          float4 o = make_float4(w * acc[m][n][0], w * acc[m][n][1],
                                 w * acc[m][n][2], w * acc[m][n][3]);
          *(float4*)((float*)Out + rowoff + n * 16) = o;
        }
      }
    }
  }
}

extern "C" void kernel_launch(void* const* d_in, const int* in_sizes, int n_in,
                              void* d_out, int out_size, void* d_ws, size_t ws_size,
                              hipStream_t stream) {
  (void)in_sizes; (void)n_in; (void)out_size; (void)ws_size;
  const float* x  = (const float*)d_in[0];
  const float* Wg = (const float*)d_in[1];
  const float* W1 = (const float*)d_in[2];
  const float* W2 = (const float*)d_in[3];
  float* out = (float*)d_out;

  char* ws = (char*)d_ws;
  size_t off = 0;
  auto alloc = [&](size_t bytes) -> void* {
    void* p = ws + off;
    off += (bytes + 255) & ~(size_t)255;
    return p;
  };
  u16* xb   = (u16*)alloc((size_t)T_TOK * DIM * 2);         // 32 MB (token-order bf16 x)
  u16* w1t  = (u16*)alloc((size_t)NE * FF * DIM * 2);       // 32 MB  [E][F][D]
  u16* w2t  = (u16*)alloc((size_t)NE * DIM * FF * 2);       // 32 MB  [E][D][F]
  u16* H    = (u16*)alloc((size_t)(T_TOK + 256) * FF * 2);  // 65 MB, padded
  float* probs  = (float*)alloc((size_t)T_TOK * NE * 4);
  float* probsT = (float*)alloc((size_t)NE * T_TOK * 4);
  u64* key      = (u64*)alloc((size_t)T_TOK * 8);
  float* wgt    = (float*)alloc((size_t)T_TOK * 4);
  int* tok2exp  = (int*)alloc((size_t)T_TOK * 4);
  int* list     = (int*)alloc((size_t)T_TOK * 4);
  int* cnt      = (int*)alloc(64);
  int* cnt2     = (int*)alloc(64);
  int* basep    = (int*)alloc(64);
  int* wl1      = (int*)alloc(WL1SZ * 4);
  int* wl2      = (int*)alloc(WL2SZ * 4);

  transpose_cvt<<<dim3(FF / 32, DIM / 32, NE), 256, 0, stream>>>(W1, w1t, DIM, FF);
  transpose_cvt<<<dim3(DIM / 32, FF / 32, NE), 256, 0, stream>>>(W2, w2t, FF, DIM);
  router_k<<<T_TOK / 4, 256, 0, stream>>>(x, Wg, probs, probsT, xb, key, cnt, cnt2);
  topk_sel<<<NE, 256, 0, stream>>>(probsT, key);
  assign_k<<<T_TOK / 256, 256, 0, stream>>>(probs, key, tok2exp, wgt, cnt);
  wl_build<<<(WL1SZ + WL2SZ) / 256, 256, 0, stream>>>(cnt, basep, wl1, wl2);
  slot_k<<<T_TOK / 256, 256, 0, stream>>>(tok2exp, basep, cnt2, list);
  ffn_k<0><<<WL1SZ, 512, 0, stream>>>(xb, w1t, H, list, wgt, basep, cnt, wl1);
  ffn_k<1><<<WL2SZ, 512, 0, stream>>>(H, w2t, out, list, wgt, basep, cnt, wl2);
}

// Round 6
// 470.541 us; speedup vs baseline: 1.2549x; 1.2549x over previous
//
#include <hip/hip_runtime.h>
#include <hip/hip_bf16.h>
#include <math.h>

// ExpertChoiceMoELayer: B=8,S=2048,D=1024,F=2048,E=8 -> T=16384, cap=2048
#define T_TOK 16384
#define DIM   1024
#define FF    2048
#define NE    8
#define CAPK  2048
#define MTE_MAX 16
#define WL1SZ (NE * 8 * MTE_MAX)  // 1024
#define WL2SZ (NE * 4 * MTE_MAX)  // 512

typedef unsigned short u16;
typedef unsigned long long u64;
typedef __attribute__((ext_vector_type(8))) short bf16x8;
typedef __attribute__((ext_vector_type(4))) float f32x4;

__device__ __forceinline__ u16 f2bf(float f) {
  __hip_bfloat16 h = __float2bfloat16(f);
  union { __hip_bfloat16 h; u16 u; } c; c.h = h; return c.u;
}

// fast GELU: 0.5x(1+erf(x/sqrt2)), erf via Abramowitz-Stegun 7.1.26 (|err|<=1.5e-7)
__device__ __forceinline__ float gelu_f(float v) {
  float z = fabsf(v) * 0.70710678118654752f;
  float t = __builtin_amdgcn_rcpf(1.0f + 0.3275911f * z);
  float poly = t * (0.254829592f +
               t * (-0.284496736f +
               t * (1.421413741f +
               t * (-1.453152027f +
               t * 1.061405429f))));
  float ez = __expf(-z * z);
  float erfz = 1.0f - poly * ez;
  erfz = copysignf(erfz, v);
  return 0.5f * v * (1.0f + erfz);
}

__device__ __forceinline__ void async_copy16(const void* g, void* l) {
  __builtin_amdgcn_global_load_lds(
      (const __attribute__((address_space(1))) unsigned int*)g,
      (__attribute__((address_space(3))) unsigned int*)l, 16, 0, 0);
}

// ---- fp32 [E][R][C] -> bf16 [E][C][R] ----
__global__ __launch_bounds__(256) void transpose_cvt(const float* __restrict__ src,
                                                     u16* __restrict__ dst, int R, int C) {
  __shared__ float tile[32][35];
  int e = blockIdx.z;
  int c0 = blockIdx.x * 32, r0 = blockIdx.y * 32;
  const float* s = src + (size_t)e * R * C;
  u16* d = dst + (size_t)e * R * C;
  int tid = threadIdx.x;
#pragma unroll
  for (int i = 0; i < 4; ++i) {
    int idx = tid + i * 256;
    int r = idx >> 5, c = idx & 31;
    tile[r][c] = s[(size_t)(r0 + r) * C + c0 + c];
  }
  __syncthreads();
  int q = tid & 7, cc = tid >> 3;
  ushort4 h;
  h.x = f2bf(tile[q * 4 + 0][cc]);
  h.y = f2bf(tile[q * 4 + 1][cc]);
  h.z = f2bf(tile[q * 4 + 2][cc]);
  h.w = f2bf(tile[q * 4 + 3][cc]);
  *(ushort4*)(d + (size_t)(c0 + cc) * R + r0 + q * 4) = h;
}

// ---- router: fp64-accum logits + softmax; probs [T][E], probsT [E][T], xb bf16;
//      also clears key/cnt/cnt2 (fused init) ----
__global__ __launch_bounds__(256) void router_k(const float* __restrict__ x,
                                                const float* __restrict__ Wg,
                                                float* __restrict__ probs,
                                                float* __restrict__ probsT,
                                                u16* __restrict__ xb,
                                                u64* __restrict__ key,
                                                int* cnt, int* cnt2) {
  int tid = threadIdx.x;
  if (tid < 4) key[blockIdx.x * 4 + tid] = 0ull;
  if (blockIdx.x == 0 && tid < NE) { cnt[tid] = 0; cnt2[tid] = 0; }
  int wid = tid >> 6, lane = tid & 63;
  int t = blockIdx.x * 4 + wid;
  const float* xr = x + (size_t)t * DIM;
  u16* xbr = xb + (size_t)t * DIM;
  double acc[NE] = {0, 0, 0, 0, 0, 0, 0, 0};
#pragma unroll 1
  for (int it = 0; it < DIM / 64; ++it) {
    int d = it * 64 + lane;
    float xv = xr[d];
    xbr[d] = f2bf(xv);
    const float4* wrow = (const float4*)(Wg + (size_t)d * NE);
    float4 w0 = wrow[0], w1 = wrow[1];
    acc[0] += (double)xv * (double)w0.x;
    acc[1] += (double)xv * (double)w0.y;
    acc[2] += (double)xv * (double)w0.z;
    acc[3] += (double)xv * (double)w0.w;
    acc[4] += (double)xv * (double)w1.x;
    acc[5] += (double)xv * (double)w1.y;
    acc[6] += (double)xv * (double)w1.z;
    acc[7] += (double)xv * (double)w1.w;
  }
#pragma unroll
  for (int e = 0; e < NE; ++e)
    for (int o = 32; o > 0; o >>= 1) acc[e] += __shfl_down(acc[e], o, 64);
  if (lane == 0) {
    float l[NE], mx = -3.0e38f;
#pragma unroll
    for (int e = 0; e < NE; ++e) { l[e] = (float)acc[e]; mx = fmaxf(mx, l[e]); }
    float s = 0.f;
#pragma unroll
    for (int e = 0; e < NE; ++e) { l[e] = expf(l[e] - mx); s += l[e]; }
    float inv = 1.0f / s;
#pragma unroll
    for (int e = 0; e < NE; ++e) {
      float p = l[e] * inv;
      probs[(size_t)t * NE + e] = p;
      probsT[(size_t)e * T_TOK + t] = p;
    }
  }
}

// ---- per-expert exact top-CAPK: 3-level radix (11/11/10 bits), per-wave L0 hist,
//      parallel shfl suffix/prefix scans (no serial tid0 loops) ----
__global__ __launch_bounds__(256) void topk_sel(const float* __restrict__ probsT,
                                                u64* __restrict__ key) {
  __shared__ float pcol[T_TOK];          // 64 KB
  __shared__ unsigned whist[8][2048];    // 64 KB (level-0 per-wave)
  __shared__ unsigned hist[2048];        // 8 KB
  __shared__ unsigned bcast[2];
  __shared__ unsigned wsum[4];
  __shared__ int wps[4];
  int e = blockIdx.x, tid = threadIdx.x, wid = tid >> 6, lane = tid & 63;
  const float4* src4 = (const float4*)(probsT + (size_t)e * T_TOK);
  for (int i = tid; i < T_TOK / 4; i += 256) ((float4*)pcol)[i] = src4[i];
  for (int i = tid; i < 8 * 2048; i += 256) ((unsigned*)whist)[i] = 0;
  unsigned prefix = 0, remaining = CAPK;
#pragma unroll 1
  for (int lvl = 0; lvl < 3; ++lvl) {
    int nb = (lvl == 2) ? 1024 : 2048;
    if (lvl == 0) {
      __syncthreads();
      for (int i = tid; i < T_TOK; i += 256)
        atomicAdd(&whist[wid][__float_as_uint(pcol[i]) >> 21], 1u);
      __syncthreads();
      for (int j = tid; j < 2048; j += 256) {
        unsigned s2 = 0;
#pragma unroll
        for (int w = 0; w < 8; ++w) s2 += whist[w][j];
        hist[j] = s2;
      }
      __syncthreads();
    } else {
      for (int i = tid; i < 2048; i += 256) hist[i] = 0;
      __syncthreads();
      for (int i = tid; i < T_TOK; i += 256) {
        unsigned k = __float_as_uint(pcol[i]);
        bool m = (lvl == 1) ? ((k >> 21) == prefix) : ((k >> 10) == prefix);
        if (m) atomicAdd(&hist[(lvl == 1) ? ((k >> 10) & 2047u) : (k & 1023u)], 1u);
      }
      __syncthreads();
    }
    int nper = nb / 256;
    unsigned cv = 0;
    for (int j = 0; j < nper; ++j) cv += hist[tid * nper + j];
    // parallel inclusive suffix scan over 256 chunk sums
    unsigned s = cv;
#pragma unroll
    for (int o = 1; o < 64; o <<= 1) {
      unsigned tv = __shfl_down(s, o, 64);
      if (lane + o < 64) s += tv;
    }
    if (lane == 0) wsum[wid] = s;
    __syncthreads();
    unsigned above = 0;
    for (int w = wid + 1; w < 4; ++w) above += wsum[w];
    unsigned Sincl = s + above, Sexcl = Sincl - cv;
    if (Sincl >= remaining && Sexcl < remaining) {   // exactly one thread
      unsigned rem2 = remaining - Sexcl, cum2 = 0;
      for (int j = nper - 1; j >= 0; --j) {
        unsigned h = hist[tid * nper + j];
        if (cum2 + h >= rem2) { bcast[0] = (unsigned)(tid * nper + j); bcast[1] = rem2 - cum2; break; }
        cum2 += h;
      }
    }
    __syncthreads();
    unsigned b = bcast[0];
    remaining = bcast[1];
    prefix = (lvl == 0) ? b : (lvl == 1) ? ((prefix << 11) | b) : ((prefix << 10) | b);
    __syncthreads();
  }
  unsigned vk = prefix;
  int need = (int)remaining;
  const int CH = T_TOK / 256;  // 64 contiguous tokens/thread
  int i0 = tid * CH;
  int myt = 0;
  for (int i = i0; i < i0 + CH; ++i)
    myt += (__float_as_uint(pcol[i]) == vk);
  // parallel exclusive prefix over 256 tie counts
  int p = myt;
#pragma unroll
  for (int o = 1; o < 64; o <<= 1) {
    int tv = __shfl_up(p, o, 64);
    if (lane >= o) p += tv;
  }
  if (lane == 63) wps[wid] = p;
  __syncthreads();
  int wo = 0;
  for (int w = 0; w < wid; ++w) wo += wps[w];
  int run = wo + p - myt;
  u64 ebits = (u64)(7 - e);
  for (int i = i0; i < i0 + CH; ++i) {
    unsigned k = __float_as_uint(pcol[i]);
    bool sv = false;
    if (k > vk) sv = true;
    else if (k == vk) { if (run < need) sv = true; run++; }
    if (sv) atomicMax(&key[i], ((u64)k << 3) | ebits);
  }
}

__global__ __launch_bounds__(256) void assign_k(const float* __restrict__ probs,
                                                const u64* __restrict__ key,
                                                int* __restrict__ tok2exp,
                                                float* __restrict__ wgt, int* cnt) {
  int t = blockIdx.x * 256 + threadIdx.x;
  int lane = threadIdx.x & 63;
  u64 k = key[t];
  int best;
  float bp;
  if (k) {
    best = 7 - (int)(k & 7);
    bp = __uint_as_float((unsigned)(k >> 3));
  } else {
    best = 0; bp = -3.0e38f;
#pragma unroll
    for (int e = 0; e < NE; ++e) {
      float p = probs[(size_t)t * NE + e];
      if (p > bp) { bp = p; best = e; }
    }
  }
  tok2exp[t] = best;
  wgt[t] = bp;
#pragma unroll
  for (int e = 0; e < NE; ++e) {
    u64 m = __ballot(best == e);
    if (best == e && lane == __ffsll(m) - 1) atomicAdd(&cnt[e], (int)__popcll(m));
  }
}

// merged: basep + XCD-local worklists + slot compaction (wave-aggregated atomics)
__global__ __launch_bounds__(256) void slot_wl_k(const int* __restrict__ tok2exp,
                                                 const int* __restrict__ cnt,
                                                 int* cnt2, int* __restrict__ list,
                                                 int* basep, int* wl1, int* wl2) {
  int gid = blockIdx.x * 256 + threadIdx.x;
  int lane = threadIdx.x & 63;
  int c[NE];
#pragma unroll
  for (int e = 0; e < NE; ++e) c[e] = cnt[e];
  if (gid < NE) {
    int r = 0;
    for (int e = 0; e < gid; ++e) r += c[e];
    basep[gid] = r;
  }
  if (gid < WL1SZ) {
    int e = gid & 7, j = gid >> 3;
    int mte = (c[e] + 255) >> 8;
    int v = -1;
    if (j < 8 * mte) {       // nt half-split: WS = A-panel + 4 B-panels < L2
      int half = 4 * mte;
      int h = (j >= half) ? 1 : 0;
      int jj = j - h * half;
      v = e | ((jj >> 2) << 4) | (((h << 2) | (jj & 3)) << 12);
    }
    wl1[gid] = v;
  }
  if (gid >= WL1SZ && gid < WL1SZ + WL2SZ) {
    int g2 = gid - WL1SZ;
    int e = g2 & 7, j = g2 >> 3;
    int mte = (c[e] + 255) >> 8;
    int v = -1;
    if (j < 4 * mte) {
      int half = 2 * mte;
      int h = (j >= half) ? 1 : 0;
      int jj = j - h * half;
      v = e | ((jj >> 1) << 4) | (((h << 1) | (jj & 1)) << 12);
    }
    wl2[g2] = v;
  }
  // slot compaction for token t = gid
  int te = tok2exp[gid];
  int bp_e = 0;
#pragma unroll
  for (int e = 0; e < NE; ++e) if (e < te) bp_e += c[e];
  int sl = 0;
#pragma unroll
  for (int e = 0; e < NE; ++e) {
    u64 m = __ballot(te == e);
    if (te == e) {
      int leader = __ffsll(m) - 1;
      int rank = __popcll(m & ((1ull << lane) - 1));
      int b = 0;
      if (lane == leader) b = atomicAdd(&cnt2[e], (int)__popcll(m));
      b = __shfl(b, leader, 64);
      sl = bp_e + b + rank;
    }
  }
  list[sl] = gid;
}

// ============ grouped GEMM: 256x256 tile, BK=32, 4-deep K-tile ring (128 KB), ============
// stage tile t+3 during t, ONE counted vmcnt + 2 barriers per tile (R4 density,
// m218-style deep drain distance ~5-6 phases), swizzled LDS, setprio, op-swapped MFMA
// EPI=0: H[slot] = GELU(xb[tok] @ W1t^T)   (K=DIM, N=FF) ; A gathered via toks
// EPI=1: out[tok] = wgt * (H[slot] @ W2t^T) (K=FF,  N=DIM) ; A dense by slot

#define MF(M, N_, AV, BV) acc[M][N_] = __builtin_amdgcn_mfma_f32_16x16x32_bf16(BV, AV, acc[M][N_], 0, 0, 0)

#define SLOT_A(s) (sm + (s) * 32768)
#define SLOT_B(s) (sm + (s) * 32768 + 16384)

#define PHASE_DSA(s, mh)                                                          \
  pa = SLOT_A(s) + wr * 8192 + (mh) * 4096 + laneOff;                             \
  a0 = *(const bf16x8*)(pa);                                                      \
  a1 = *(const bf16x8*)(pa + 1024);                                               \
  a2 = *(const bf16x8*)(pa + 2048);                                               \
  a3 = *(const bf16x8*)(pa + 3072);

#define PHASE_DSB(s)                                                              \
  pb = SLOT_B(s) + wc * 4096 + laneOff;                                           \
  b0 = *(const bf16x8*)(pb);                                                      \
  b1 = *(const bf16x8*)(pb + 1024);                                               \
  b2 = *(const bf16x8*)(pb + 2048);                                               \
  b3 = *(const bf16x8*)(pb + 3072);

#define PHASE_MFMA(mh)                                                            \
  do {                                                                            \
    __builtin_amdgcn_s_setprio(1);                                                \
    MF((mh) * 4 + 0, 0, a0, b0); MF((mh) * 4 + 0, 1, a0, b1);                     \
    MF((mh) * 4 + 0, 2, a0, b2); MF((mh) * 4 + 0, 3, a0, b3);                     \
    MF((mh) * 4 + 1, 0, a1, b0); MF((mh) * 4 + 1, 1, a1, b1);                     \
    MF((mh) * 4 + 1, 2, a1, b2); MF((mh) * 4 + 1, 3, a1, b3);                     \
    MF((mh) * 4 + 2, 0, a2, b0); MF((mh) * 4 + 2, 1, a2, b1);                     \
    MF((mh) * 4 + 2, 2, a2, b2); MF((mh) * 4 + 2, 3, a2, b3);                     \
    MF((mh) * 4 + 3, 0, a3, b0); MF((mh) * 4 + 3, 1, a3, b1);                     \
    MF((mh) * 4 + 3, 2, a3, b2); MF((mh) * 4 + 3, 3, a3, b3);                     \
    __builtin_amdgcn_s_setprio(0);                                                \
  } while (0)

#define STAGE_A(s, kt)                                                            \
  do {                                                                            \
    async_copy16(aP0 + (size_t)(kt) * 64, SLOT_A(s) + wid * 1024);                \
    async_copy16(aP1 + (size_t)(kt) * 64, SLOT_A(s) + 8192 + wid * 1024);         \
  } while (0)

#define STAGE_B(s, kt)                                                            \
  do {                                                                            \
    async_copy16(bP0 + (size_t)(kt) * 64, SLOT_B(s) + wid * 1024);                \
    async_copy16(bP1 + (size_t)(kt) * 64, SLOT_B(s) + 8192 + wid * 1024);         \
  } while (0)

#define BAR() asm volatile("s_barrier" ::: "memory")

template <int EPI>
__global__ __launch_bounds__(512, 2) void ffn_k(const u16* __restrict__ A,
                                                const u16* __restrict__ Bm,
                                                void* __restrict__ Out,
                                                const int* __restrict__ list,
                                                const float* __restrict__ wgt,
                                                const int* __restrict__ basep,
                                                const int* __restrict__ cnt,
                                                const int* __restrict__ wl) {
  constexpr int K = EPI ? FF : DIM;
  constexpr int N = EPI ? DIM : FF;
  constexpr int KT = K / 32;

  const int wle = wl[blockIdx.x];
  if (wle < 0) return;
  const int e = wle & 15, mt = (wle >> 4) & 255, nt = wle >> 12;
  const int ce = cnt[e];
  const int be = basep[e];

  __shared__ u16 smem[65536];   // 128 KiB: 4 ring slots x (A 16KB + B 16KB)
  __shared__ int toks[256];
  __shared__ float wsc[256];
  char* const sm = (char*)smem;

  const int tid = threadIdx.x;
  if (tid < 256) {
    int r = mt * 256 + tid;
    int tk = (r < ce) ? list[be + r] : list[be];
    toks[tid] = tk;
    if (EPI == 1) wsc[tid] = wgt[tk];
  }
  __syncthreads();

  const int wid = tid >> 6, lane = tid & 63;
  const int wr = wid >> 2, wc = wid & 3;
  // swizzled per-lane frag-read offset (2 rows per 128B line, XOR on line&3)
  const int laneOff = ((lane & 15) >> 1) * 128 + (lane & 1) * 64 +
                      (((lane >> 4) << 4) ^ (((lane >> 1) & 3) << 4));

  // staging: thread covers tile rows tr0 (call 0) and tr1=tr0+128 (call 1)
  const int tr0 = ((tid >> 3) << 1) + ((tid >> 2) & 1), tr1 = 128 + tr0;
  const int cbl = ((tid & 3) << 4) ^ (((tid >> 3) & 3) << 4);
  const char *aP0, *aP1;
  if (EPI == 0) {
    aP0 = (const char*)(A + (size_t)toks[tr0] * K) + cbl;
    aP1 = (const char*)(A + (size_t)toks[tr1] * K) + cbl;
  } else {
    aP0 = (const char*)(A + ((size_t)be + mt * 256 + tr0) * K) + cbl;
    aP1 = (const char*)(A + ((size_t)be + mt * 256 + tr1) * K) + cbl;
  }
  const char* bP0 = (const char*)(Bm + ((size_t)e * N + nt * 256 + tr0) * K) + cbl;
  const char* bP1 = (const char*)(Bm + ((size_t)e * N + nt * 256 + tr1) * K) + cbl;

  f32x4 acc[8][4];
#pragma unroll
  for (int m = 0; m < 8; ++m)
#pragma unroll
    for (int n = 0; n < 4; ++n) acc[m][n] = (f32x4){0.f, 0.f, 0.f, 0.f};

  // prologue: stage slots 0,1,2 (3 K-tiles ahead = 12 loads)
  STAGE_A(0, 0); STAGE_B(0, 0);
  STAGE_A(1, 1); STAGE_B(1, 1);
  STAGE_A(2, 2); STAGE_B(2, 2);
  asm volatile("s_waitcnt vmcnt(8)" ::: "memory");  // tile 0 landed
  BAR();

  const char* pa;
  const char* pb;
  bf16x8 a0, a1, a2, a3, b0, b1, b2, b3;

#pragma unroll 1
  for (int kt = 0; kt < KT; ++kt) {
    const int s = kt & 3, sn = (kt + 3) & 3;
    const bool pf = (kt + 3 < KT);
    // P1: issue A-prefetch (tile kt+3); read mh0 + B frags; barrier; MFMA
    if (pf) STAGE_A(sn, kt + 3);
    PHASE_DSA(s, 0);
    PHASE_DSB(s);
    BAR();
    PHASE_MFMA(0);
    // P2: issue B-prefetch; read mh1 frags; ONE counted wait -> tile kt+1 landed
    if (pf) STAGE_B(sn, kt + 3);
    PHASE_DSA(s, 1);
    if (kt < KT - 3)       asm volatile("s_waitcnt vmcnt(8)" ::: "memory");
    else if (kt == KT - 3) asm volatile("s_waitcnt vmcnt(4)" ::: "memory");
    else if (kt == KT - 2) asm volatile("s_waitcnt vmcnt(0)" ::: "memory");
    BAR();
    PHASE_MFMA(1);
  }

  // epilogue: operand-swap => acc reg index runs along output cols -> vector stores
  const int lc = lane & 15, lq = (lane >> 4) * 4;
#pragma unroll
  for (int m = 0; m < 8; ++m) {
    int trow = wr * 128 + m * 16 + lc;
    int grow = mt * 256 + trow;
    if (grow < ce) {
      if (EPI == 0) {
        size_t rowoff = (size_t)(be + grow) * FF + nt * 256 + wc * 64 + lq;
#pragma unroll
        for (int n = 0; n < 4; ++n) {
          ushort4 h4;
          h4.x = f2bf(gelu_f(acc[m][n][0]));
          h4.y = f2bf(gelu_f(acc[m][n][1]));
          h4.z = f2bf(gelu_f(acc[m][n][2]));
          h4.w = f2bf(gelu_f(acc[m][n][3]));
          *(ushort4*)((u16*)Out + rowoff + n * 16) = h4;
        }
      } else {
        float w = wsc[trow];
        size_t rowoff = (size_t)toks[trow] * DIM + nt * 256 + wc * 64 + lq;
#pragma unroll
        for (int n = 0; n < 4; ++n) {
          float4 o = make_float4(w * acc[m][n][0], w * acc[m][n][1],
                                 w * acc[m][n][2], w * acc[m][n][3]);
          *(float4*)((float*)Out + rowoff + n * 16) = o;
        }
      }
    }
  }
}

extern "C" void kernel_launch(void* const* d_in, const int* in_sizes, int n_in,
                              void* d_out, int out_size, void* d_ws, size_t ws_size,
                              hipStream_t stream) {
  (void)in_sizes; (void)n_in; (void)out_size; (void)ws_size;
  const float* x  = (const float*)d_in[0];
  const float* Wg = (const float*)d_in[1];
  const float* W1 = (const float*)d_in[2];
  const float* W2 = (const float*)d_in[3];
  float* out = (float*)d_out;

  char* ws = (char*)d_ws;
  size_t off = 0;
  auto alloc = [&](size_t bytes) -> void* {
    void* p = ws + off;
    off += (bytes + 255) & ~(size_t)255;
    return p;
  };
  u16* xb   = (u16*)alloc((size_t)T_TOK * DIM * 2);         // 32 MB (token-order bf16 x)
  u16* w1t  = (u16*)alloc((size_t)NE * FF * DIM * 2);       // 32 MB  [E][F][D]
  u16* w2t  = (u16*)alloc((size_t)NE * DIM * FF * 2);       // 32 MB  [E][D][F]
  u16* H    = (u16*)alloc((size_t)(T_TOK + 256) * FF * 2);  // 65 MB, padded
  float* probs  = (float*)alloc((size_t)T_TOK * NE * 4);
  float* probsT = (float*)alloc((size_t)NE * T_TOK * 4);
  u64* key      = (u64*)alloc((size_t)T_TOK * 8);
  float* wgt    = (float*)alloc((size_t)T_TOK * 4);
  int* tok2exp  = (int*)alloc((size_t)T_TOK * 4);
  int* list     = (int*)alloc((size_t)T_TOK * 4);
  int* cnt      = (int*)alloc(64);
  int* cnt2     = (int*)alloc(64);
  int* basep    = (int*)alloc(64);
  int* wl1      = (int*)alloc(WL1SZ * 4);
  int* wl2      = (int*)alloc(WL2SZ * 4);

  transpose_cvt<<<dim3(FF / 32, DIM / 32, NE), 256, 0, stream>>>(W1, w1t, DIM, FF);
  transpose_cvt<<<dim3(DIM / 32, FF / 32, NE), 256, 0, stream>>>(W2, w2t, FF, DIM);
  router_k<<<T_TOK / 4, 256, 0, stream>>>(x, Wg, probs, probsT, xb, key, cnt, cnt2);
  topk_sel<<<NE, 256, 0, stream>>>(probsT, key);
  assign_k<<<T_TOK / 256, 256, 0, stream>>>(probs, key, tok2exp, wgt, cnt);
  slot_wl_k<<<T_TOK / 256, 256, 0, stream>>>(tok2exp, cnt, cnt2, list, basep, wl1, wl2);
  ffn_k<0><<<WL1SZ, 512, 0, stream>>>(xb, w1t, H, list, wgt, basep, cnt, wl1);
  ffn_k<1><<<WL2SZ, 512, 0, stream>>>(H, w2t, out, list, wgt, basep, cnt, wl2);
}

// Round 7
// 397.199 us; speedup vs baseline: 1.4866x; 1.1846x over previous
//
#include <hip/hip_runtime.h>
#include <hip/hip_bf16.h>
#include <math.h>

// ExpertChoiceMoELayer: B=8,S=2048,D=1024,F=2048,E=8 -> T=16384, cap=2048
#define T_TOK 16384
#define DIM   1024
#define FF    2048
#define NE    8
#define CAPK  2048
#define MTE_MAX 16
#define WL1SZ (NE * 8 * MTE_MAX)  // 1024
#define WL2SZ (NE * 4 * MTE_MAX)  // 512

typedef unsigned short u16;
typedef unsigned long long u64;
typedef __attribute__((ext_vector_type(8))) short bf16x8;
typedef __attribute__((ext_vector_type(4))) float f32x4;

__device__ __forceinline__ u16 f2bf(float f) {
  __hip_bfloat16 h = __float2bfloat16(f);
  union { __hip_bfloat16 h; u16 u; } c; c.h = h; return c.u;
}

// fast GELU: 0.5x(1+erf(x/sqrt2)), erf via Abramowitz-Stegun 7.1.26 (|err|<=1.5e-7)
__device__ __forceinline__ float gelu_f(float v) {
  float z = fabsf(v) * 0.70710678118654752f;
  float t = __builtin_amdgcn_rcpf(1.0f + 0.3275911f * z);
  float poly = t * (0.254829592f +
               t * (-0.284496736f +
               t * (1.421413741f +
               t * (-1.453152027f +
               t * 1.061405429f))));
  float ez = __expf(-z * z);
  float erfz = 1.0f - poly * ez;
  erfz = copysignf(erfz, v);
  return 0.5f * v * (1.0f + erfz);
}

__device__ __forceinline__ void async_copy16(const void* g, void* l) {
  __builtin_amdgcn_global_load_lds(
      (const __attribute__((address_space(1))) unsigned int*)g,
      (__attribute__((address_space(3))) unsigned int*)l, 16, 0, 0);
}

// opaque LDS read: compiler's waitcnt pass cannot see this as a ds op, so it
// won't insert vmcnt(0) drains to order it against pending global_load_lds DMA.
// We enforce correctness ourselves via counted vmcnt + barrier + lgkmcnt(0).
__device__ __forceinline__ bf16x8 ds_read16(const char* p) {
  bf16x8 r;
  asm volatile("ds_read_b128 %0, %1"
               : "=&v"(r)
               : "v"((const __attribute__((address_space(3))) char*)p));
  return r;
}

// ---- fp32 [E][R][C] -> bf16 [E][C][R] ----
__global__ __launch_bounds__(256) void transpose_cvt(const float* __restrict__ src,
                                                     u16* __restrict__ dst, int R, int C) {
  __shared__ float tile[32][35];
  int e = blockIdx.z;
  int c0 = blockIdx.x * 32, r0 = blockIdx.y * 32;
  const float* s = src + (size_t)e * R * C;
  u16* d = dst + (size_t)e * R * C;
  int tid = threadIdx.x;
#pragma unroll
  for (int i = 0; i < 4; ++i) {
    int idx = tid + i * 256;
    int r = idx >> 5, c = idx & 31;
    tile[r][c] = s[(size_t)(r0 + r) * C + c0 + c];
  }
  __syncthreads();
  int q = tid & 7, cc = tid >> 3;
  ushort4 h;
  h.x = f2bf(tile[q * 4 + 0][cc]);
  h.y = f2bf(tile[q * 4 + 1][cc]);
  h.z = f2bf(tile[q * 4 + 2][cc]);
  h.w = f2bf(tile[q * 4 + 3][cc]);
  *(ushort4*)(d + (size_t)(c0 + cc) * R + r0 + q * 4) = h;
}

// ---- router: fp64-accum logits + softmax; probs [T][E], probsT [E][T], xb bf16;
//      also clears key/cnt/cnt2 (fused init) ----
__global__ __launch_bounds__(256) void router_k(const float* __restrict__ x,
                                                const float* __restrict__ Wg,
                                                float* __restrict__ probs,
                                                float* __restrict__ probsT,
                                                u16* __restrict__ xb,
                                                u64* __restrict__ key,
                                                int* cnt, int* cnt2) {
  int tid = threadIdx.x;
  if (tid < 4) key[blockIdx.x * 4 + tid] = 0ull;
  if (blockIdx.x == 0 && tid < NE) { cnt[tid] = 0; cnt2[tid] = 0; }
  int wid = tid >> 6, lane = tid & 63;
  int t = blockIdx.x * 4 + wid;
  const float* xr = x + (size_t)t * DIM;
  u16* xbr = xb + (size_t)t * DIM;
  double acc[NE] = {0, 0, 0, 0, 0, 0, 0, 0};
#pragma unroll 1
  for (int it = 0; it < DIM / 64; ++it) {
    int d = it * 64 + lane;
    float xv = xr[d];
    xbr[d] = f2bf(xv);
    const float4* wrow = (const float4*)(Wg + (size_t)d * NE);
    float4 w0 = wrow[0], w1 = wrow[1];
    acc[0] += (double)xv * (double)w0.x;
    acc[1] += (double)xv * (double)w0.y;
    acc[2] += (double)xv * (double)w0.z;
    acc[3] += (double)xv * (double)w0.w;
    acc[4] += (double)xv * (double)w1.x;
    acc[5] += (double)xv * (double)w1.y;
    acc[6] += (double)xv * (double)w1.z;
    acc[7] += (double)xv * (double)w1.w;
  }
#pragma unroll
  for (int e = 0; e < NE; ++e)
    for (int o = 32; o > 0; o >>= 1) acc[e] += __shfl_down(acc[e], o, 64);
  if (lane == 0) {
    float l[NE], mx = -3.0e38f;
#pragma unroll
    for (int e = 0; e < NE; ++e) { l[e] = (float)acc[e]; mx = fmaxf(mx, l[e]); }
    float s = 0.f;
#pragma unroll
    for (int e = 0; e < NE; ++e) { l[e] = expf(l[e] - mx); s += l[e]; }
    float inv = 1.0f / s;
#pragma unroll
    for (int e = 0; e < NE; ++e) {
      float p = l[e] * inv;
      probs[(size_t)t * NE + e] = p;
      probsT[(size_t)e * T_TOK + t] = p;
    }
  }
}

// ---- per-expert exact top-CAPK: 3-level radix (11/11/10 bits), per-wave L0 hist,
//      parallel shfl suffix/prefix scans ----
__global__ __launch_bounds__(256) void topk_sel(const float* __restrict__ probsT,
                                                u64* __restrict__ key) {
  __shared__ float pcol[T_TOK];          // 64 KB
  __shared__ unsigned whist[8][2048];    // 64 KB (level-0 per-wave)
  __shared__ unsigned hist[2048];        // 8 KB
  __shared__ unsigned bcast[2];
  __shared__ unsigned wsum[4];
  __shared__ int wps[4];
  int e = blockIdx.x, tid = threadIdx.x, wid = tid >> 6, lane = tid & 63;
  const float4* src4 = (const float4*)(probsT + (size_t)e * T_TOK);
  for (int i = tid; i < T_TOK / 4; i += 256) ((float4*)pcol)[i] = src4[i];
  for (int i = tid; i < 8 * 2048; i += 256) ((unsigned*)whist)[i] = 0;
  unsigned prefix = 0, remaining = CAPK;
#pragma unroll 1
  for (int lvl = 0; lvl < 3; ++lvl) {
    int nb = (lvl == 2) ? 1024 : 2048;
    if (lvl == 0) {
      __syncthreads();
      for (int i = tid; i < T_TOK; i += 256)
        atomicAdd(&whist[wid][__float_as_uint(pcol[i]) >> 21], 1u);
      __syncthreads();
      for (int j = tid; j < 2048; j += 256) {
        unsigned s2 = 0;
#pragma unroll
        for (int w = 0; w < 8; ++w) s2 += whist[w][j];
        hist[j] = s2;
      }
      __syncthreads();
    } else {
      for (int i = tid; i < 2048; i += 256) hist[i] = 0;
      __syncthreads();
      for (int i = tid; i < T_TOK; i += 256) {
        unsigned k = __float_as_uint(pcol[i]);
        bool m = (lvl == 1) ? ((k >> 21) == prefix) : ((k >> 10) == prefix);
        if (m) atomicAdd(&hist[(lvl == 1) ? ((k >> 10) & 2047u) : (k & 1023u)], 1u);
      }
      __syncthreads();
    }
    int nper = nb / 256;
    unsigned cv = 0;
    for (int j = 0; j < nper; ++j) cv += hist[tid * nper + j];
    unsigned s = cv;
#pragma unroll
    for (int o = 1; o < 64; o <<= 1) {
      unsigned tv = __shfl_down(s, o, 64);
      if (lane + o < 64) s += tv;
    }
    if (lane == 0) wsum[wid] = s;
    __syncthreads();
    unsigned above = 0;
    for (int w = wid + 1; w < 4; ++w) above += wsum[w];
    unsigned Sincl = s + above, Sexcl = Sincl - cv;
    if (Sincl >= remaining && Sexcl < remaining) {
      unsigned rem2 = remaining - Sexcl, cum2 = 0;
      for (int j = nper - 1; j >= 0; --j) {
        unsigned h = hist[tid * nper + j];
        if (cum2 + h >= rem2) { bcast[0] = (unsigned)(tid * nper + j); bcast[1] = rem2 - cum2; break; }
        cum2 += h;
      }
    }
    __syncthreads();
    unsigned b = bcast[0];
    remaining = bcast[1];
    prefix = (lvl == 0) ? b : (lvl == 1) ? ((prefix << 11) | b) : ((prefix << 10) | b);
    __syncthreads();
  }
  unsigned vk = prefix;
  int need = (int)remaining;
  const int CH = T_TOK / 256;
  int i0 = tid * CH;
  int myt = 0;
  for (int i = i0; i < i0 + CH; ++i)
    myt += (__float_as_uint(pcol[i]) == vk);
  int p = myt;
#pragma unroll
  for (int o = 1; o < 64; o <<= 1) {
    int tv = __shfl_up(p, o, 64);
    if (lane >= o) p += tv;
  }
  if (lane == 63) wps[wid] = p;
  __syncthreads();
  int wo = 0;
  for (int w = 0; w < wid; ++w) wo += wps[w];
  int run = wo + p - myt;
  u64 ebits = (u64)(7 - e);
  for (int i = i0; i < i0 + CH; ++i) {
    unsigned k = __float_as_uint(pcol[i]);
    bool sv = false;
    if (k > vk) sv = true;
    else if (k == vk) { if (run < need) sv = true; run++; }
    if (sv) atomicMax(&key[i], ((u64)k << 3) | ebits);
  }
}

__global__ __launch_bounds__(256) void assign_k(const float* __restrict__ probs,
                                                const u64* __restrict__ key,
                                                int* __restrict__ tok2exp,
                                                float* __restrict__ wgt, int* cnt) {
  int t = blockIdx.x * 256 + threadIdx.x;
  int lane = threadIdx.x & 63;
  u64 k = key[t];
  int best;
  float bp;
  if (k) {
    best = 7 - (int)(k & 7);
    bp = __uint_as_float((unsigned)(k >> 3));
  } else {
    best = 0; bp = -3.0e38f;
#pragma unroll
    for (int e = 0; e < NE; ++e) {
      float p = probs[(size_t)t * NE + e];
      if (p > bp) { bp = p; best = e; }
    }
  }
  tok2exp[t] = best;
  wgt[t] = bp;
#pragma unroll
  for (int e = 0; e < NE; ++e) {
    u64 m = __ballot(best == e);
    if (best == e && lane == __ffsll(m) - 1) atomicAdd(&cnt[e], (int)__popcll(m));
  }
}

// merged: basep + XCD-local worklists + slot compaction (wave-aggregated atomics)
__global__ __launch_bounds__(256) void slot_wl_k(const int* __restrict__ tok2exp,
                                                 const int* __restrict__ cnt,
                                                 int* cnt2, int* __restrict__ list,
                                                 int* basep, int* wl1, int* wl2) {
  int gid = blockIdx.x * 256 + threadIdx.x;
  int lane = threadIdx.x & 63;
  int c[NE];
#pragma unroll
  for (int e = 0; e < NE; ++e) c[e] = cnt[e];
  if (gid < NE) {
    int r = 0;
    for (int e = 0; e < gid; ++e) r += c[e];
    basep[gid] = r;
  }
  if (gid < WL1SZ) {
    int e = gid & 7, j = gid >> 3;
    int mte = (c[e] + 255) >> 8;
    int v = -1;
    if (j < 8 * mte) {
      int half = 4 * mte;
      int h = (j >= half) ? 1 : 0;
      int jj = j - h * half;
      v = e | ((jj >> 2) << 4) | (((h << 2) | (jj & 3)) << 12);
    }
    wl1[gid] = v;
  }
  if (gid >= WL1SZ && gid < WL1SZ + WL2SZ) {
    int g2 = gid - WL1SZ;
    int e = g2 & 7, j = g2 >> 3;
    int mte = (c[e] + 255) >> 8;
    int v = -1;
    if (j < 4 * mte) {
      int half = 2 * mte;
      int h = (j >= half) ? 1 : 0;
      int jj = j - h * half;
      v = e | ((jj >> 1) << 4) | (((h << 1) | (jj & 1)) << 12);
    }
    wl2[g2] = v;
  }
  int te = tok2exp[gid];
  int bp_e = 0;
#pragma unroll
  for (int e = 0; e < NE; ++e) if (e < te) bp_e += c[e];
  int sl = 0;
#pragma unroll
  for (int e = 0; e < NE; ++e) {
    u64 m = __ballot(te == e);
    if (te == e) {
      int leader = __ffsll(m) - 1;
      int rank = __popcll(m & ((1ull << lane) - 1));
      int b = 0;
      if (lane == leader) b = atomicAdd(&cnt2[e], (int)__popcll(m));
      b = __shfl(b, leader, 64);
      sl = bp_e + b + rank;
    }
  }
  list[sl] = gid;
}

// ============ grouped GEMM: 256x256 tile, BK=32, 4-deep K-tile ring (128 KB), ============
// stage tile t+3 during t, counted vmcnt (8/4/0), ASM ds_read (no compiler vmcnt drains),
// lgkmcnt(0)+sched_barrier(0) before each MFMA cluster, swizzled LDS, setprio
// EPI=0: H[slot] = GELU(xb[tok] @ W1t^T)   (K=DIM, N=FF) ; A gathered via toks
// EPI=1: out[tok] = wgt * (H[slot] @ W2t^^T) (K=FF,  N=DIM) ; A dense by slot

#define MF(M, N_, AV, BV) acc[M][N_] = __builtin_amdgcn_mfma_f32_16x16x32_bf16(BV, AV, acc[M][N_], 0, 0, 0)

#define SLOT_A(s) (sm + (s) * 32768)
#define SLOT_B(s) (sm + (s) * 32768 + 16384)

#define PHASE_DSA(s, mh)                                                          \
  pa = SLOT_A(s) + wr * 8192 + (mh) * 4096 + laneOff;                             \
  a0 = ds_read16(pa);                                                             \
  a1 = ds_read16(pa + 1024);                                                      \
  a2 = ds_read16(pa + 2048);                                                      \
  a3 = ds_read16(pa + 3072);

#define PHASE_DSB(s)                                                              \
  pb = SLOT_B(s) + wc * 4096 + laneOff;                                           \
  b0 = ds_read16(pb);                                                             \
  b1 = ds_read16(pb + 1024);                                                      \
  b2 = ds_read16(pb + 2048);                                                      \
  b3 = ds_read16(pb + 3072);

#define WAIT_LGKM()                                                               \
  do {                                                                            \
    asm volatile("s_waitcnt lgkmcnt(0)" ::: "memory");                            \
    __builtin_amdgcn_sched_barrier(0);                                            \
  } while (0)

#define PHASE_MFMA(mh)                                                            \
  do {                                                                            \
    __builtin_amdgcn_s_setprio(1);                                                \
    MF((mh) * 4 + 0, 0, a0, b0); MF((mh) * 4 + 0, 1, a0, b1);                     \
    MF((mh) * 4 + 0, 2, a0, b2); MF((mh) * 4 + 0, 3, a0, b3);                     \
    MF((mh) * 4 + 1, 0, a1, b0); MF((mh) * 4 + 1, 1, a1, b1);                     \
    MF((mh) * 4 + 1, 2, a1, b2); MF((mh) * 4 + 1, 3, a1, b3);                     \
    MF((mh) * 4 + 2, 0, a2, b0); MF((mh) * 4 + 2, 1, a2, b1);                     \
    MF((mh) * 4 + 2, 2, a2, b2); MF((mh) * 4 + 2, 3, a2, b3);                     \
    MF((mh) * 4 + 3, 0, a3, b0); MF((mh) * 4 + 3, 1, a3, b1);                     \
    MF((mh) * 4 + 3, 2, a3, b2); MF((mh) * 4 + 3, 3, a3, b3);                     \
    __builtin_amdgcn_s_setprio(0);                                                \
  } while (0)

#define STAGE_A(s, kt)                                                            \
  do {                                                                            \
    async_copy16(aP0 + (size_t)(kt) * 64, SLOT_A(s) + wid * 1024);                \
    async_copy16(aP1 + (size_t)(kt) * 64, SLOT_A(s) + 8192 + wid * 1024);         \
  } while (0)

#define STAGE_B(s, kt)                                                            \
  do {                                                                            \
    async_copy16(bP0 + (size_t)(kt) * 64, SLOT_B(s) + wid * 1024);                \
    async_copy16(bP1 + (size_t)(kt) * 64, SLOT_B(s) + 8192 + wid * 1024);         \
  } while (0)

#define BAR() asm volatile("s_barrier" ::: "memory")

template <int EPI>
__global__ __launch_bounds__(512, 2) void ffn_k(const u16* __restrict__ A,
                                                const u16* __restrict__ Bm,
                                                void* __restrict__ Out,
                                                const int* __restrict__ list,
                                                const float* __restrict__ wgt,
                                                const int* __restrict__ basep,
                                                const int* __restrict__ cnt,
                                                const int* __restrict__ wl) {
  constexpr int K = EPI ? FF : DIM;
  constexpr int N = EPI ? DIM : FF;
  constexpr int KT = K / 32;

  const int wle = wl[blockIdx.x];
  if (wle < 0) return;
  const int e = wle & 15, mt = (wle >> 4) & 255, nt = wle >> 12;
  const int ce = cnt[e];
  const int be = basep[e];

  __shared__ u16 smem[65536];   // 128 KiB: 4 ring slots x (A 16KB + B 16KB)
  __shared__ int toks[256];
  __shared__ float wsc[256];
  char* const sm = (char*)smem;

  const int tid = threadIdx.x;
  if (tid < 256) {
    int r = mt * 256 + tid;
    int tk = (r < ce) ? list[be + r] : list[be];
    toks[tid] = tk;
    if (EPI == 1) wsc[tid] = wgt[tk];
  }
  __syncthreads();

  const int wid = tid >> 6, lane = tid & 63;
  const int wr = wid >> 2, wc = wid & 3;
  // swizzled per-lane frag-read offset (2 rows per 128B line, XOR on line&3)
  const int laneOff = ((lane & 15) >> 1) * 128 + (lane & 1) * 64 +
                      (((lane >> 4) << 4) ^ (((lane >> 1) & 3) << 4));

  // staging: thread covers tile rows tr0 (call 0) and tr1=tr0+128 (call 1)
  const int tr0 = ((tid >> 3) << 1) + ((tid >> 2) & 1), tr1 = 128 + tr0;
  const int cbl = ((tid & 3) << 4) ^ (((tid >> 3) & 3) << 4);
  const char *aP0, *aP1;
  if (EPI == 0) {
    aP0 = (const char*)(A + (size_t)toks[tr0] * K) + cbl;
    aP1 = (const char*)(A + (size_t)toks[tr1] * K) + cbl;
  } else {
    aP0 = (const char*)(A + ((size_t)be + mt * 256 + tr0) * K) + cbl;
    aP1 = (const char*)(A + ((size_t)be + mt * 256 + tr1) * K) + cbl;
  }
  const char* bP0 = (const char*)(Bm + ((size_t)e * N + nt * 256 + tr0) * K) + cbl;
  const char* bP1 = (const char*)(Bm + ((size_t)e * N + nt * 256 + tr1) * K) + cbl;

  f32x4 acc[8][4];
#pragma unroll
  for (int m = 0; m < 8; ++m)
#pragma unroll
    for (int n = 0; n < 4; ++n) acc[m][n] = (f32x4){0.f, 0.f, 0.f, 0.f};

  // prologue: stage slots 0,1,2 (3 K-tiles ahead = 12 loads)
  STAGE_A(0, 0); STAGE_B(0, 0);
  STAGE_A(1, 1); STAGE_B(1, 1);
  STAGE_A(2, 2); STAGE_B(2, 2);
  asm volatile("s_waitcnt vmcnt(8)" ::: "memory");  // tile 0 landed
  BAR();

  const char* pa;
  const char* pb;
  bf16x8 a0, a1, a2, a3, b0, b1, b2, b3;

#pragma unroll 1
  for (int kt = 0; kt < KT; ++kt) {
    const int s = kt & 3, sn = (kt + 3) & 3;
    const bool pf = (kt + 3 < KT);
    // P1: issue A-prefetch (tile kt+3); asm ds_read mh0 + B frags; barrier;
    //     lgkmcnt drain; MFMA
    if (pf) STAGE_A(sn, kt + 3);
    PHASE_DSA(s, 0);
    PHASE_DSB(s);
    BAR();
    WAIT_LGKM();
    PHASE_MFMA(0);
    // P2: issue B-prefetch; asm ds_read mh1; ONE counted vmcnt -> tile kt+1 landed
    if (pf) STAGE_B(sn, kt + 3);
    PHASE_DSA(s, 1);
    if (kt < KT - 3)       asm volatile("s_waitcnt vmcnt(8)" ::: "memory");
    else if (kt == KT - 3) asm volatile("s_waitcnt vmcnt(4)" ::: "memory");
    else if (kt == KT - 2) asm volatile("s_waitcnt vmcnt(0)" ::: "memory");
    BAR();
    WAIT_LGKM();
    PHASE_MFMA(1);
  }

  // epilogue: operand-swap => acc reg index runs along output cols -> vector stores
  const int lc = lane & 15, lq = (lane >> 4) * 4;
#pragma unroll
  for (int m = 0; m < 8; ++m) {
    int trow = wr * 128 + m * 16 + lc;
    int grow = mt * 256 + trow;
    if (grow < ce) {
      if (EPI == 0) {
        size_t rowoff = (size_t)(be + grow) * FF + nt * 256 + wc * 64 + lq;
#pragma unroll
        for (int n = 0; n < 4; ++n) {
          ushort4 h4;
          h4.x = f2bf(gelu_f(acc[m][n][0]));
          h4.y = f2bf(gelu_f(acc[m][n][1]));
          h4.z = f2bf(gelu_f(acc[m][n][2]));
          h4.w = f2bf(gelu_f(acc[m][n][3]));
          *(ushort4*)((u16*)Out + rowoff + n * 16) = h4;
        }
      } else {
        float w = wsc[trow];
        size_t rowoff = (size_t)toks[trow] * DIM + nt * 256 + wc * 64 + lq;
#pragma unroll
        for (int n = 0; n < 4; ++n) {
          float4 o = make_float4(w * acc[m][n][0], w * acc[m][n][1],
                                 w * acc[m][n][2], w * acc[m][n][3]);
          *(float4*)((float*)Out + rowoff + n * 16) = o;
        }
      }
    }
  }
}

extern "C" void kernel_launch(void* const* d_in, const int* in_sizes, int n_in,
                              void* d_out, int out_size, void* d_ws, size_t ws_size,
                              hipStream_t stream) {
  (void)in_sizes; (void)n_in; (void)out_size; (void)ws_size;
  const float* x  = (const float*)d_in[0];
  const float* Wg = (const float*)d_in[1];
  const float* W1 = (const float*)d_in[2];
  const float* W2 = (const float*)d_in[3];
  float* out = (float*)d_out;

  char* ws = (char*)d_ws;
  size_t off = 0;
  auto alloc = [&](size_t bytes) -> void* {
    void* p = ws + off;
    off += (bytes + 255) & ~(size_t)255;
    return p;
  };
  u16* xb   = (u16*)alloc((size_t)T_TOK * DIM * 2);         // 32 MB (token-order bf16 x)
  u16* w1t  = (u16*)alloc((size_t)NE * FF * DIM * 2);       // 32 MB  [E][F][D]
  u16* w2t  = (u16*)alloc((size_t)NE * DIM * FF * 2);       // 32 MB  [E][D][F]
  u16* H    = (u16*)alloc((size_t)(T_TOK + 256) * FF * 2);  // 65 MB, padded
  float* probs  = (float*)alloc((size_t)T_TOK * NE * 4);
  float* probsT = (float*)alloc((size_t)NE * T_TOK * 4);
  u64* key      = (u64*)alloc((size_t)T_TOK * 8);
  float* wgt    = (float*)alloc((size_t)T_TOK * 4);
  int* tok2exp  = (int*)alloc((size_t)T_TOK * 4);
  int* list     = (int*)alloc((size_t)T_TOK * 4);
  int* cnt      = (int*)alloc(64);
  int* cnt2     = (int*)alloc(64);
  int* basep    = (int*)alloc(64);
  int* wl1      = (int*)alloc(WL1SZ * 4);
  int* wl2      = (int*)alloc(WL2SZ * 4);

  transpose_cvt<<<dim3(FF / 32, DIM / 32, NE), 256, 0, stream>>>(W1, w1t, DIM, FF);
  transpose_cvt<<<dim3(DIM / 32, FF / 32, NE), 256, 0, stream>>>(W2, w2t, FF, DIM);
  router_k<<<T_TOK / 4, 256, 0, stream>>>(x, Wg, probs, probsT, xb, key, cnt, cnt2);
  topk_sel<<<NE, 256, 0, stream>>>(probsT, key);
  assign_k<<<T_TOK / 256, 256, 0, stream>>>(probs, key, tok2exp, wgt, cnt);
  slot_wl_k<<<T_TOK / 256, 256, 0, stream>>>(tok2exp, cnt, cnt2, list, basep, wl1, wl2);
  ffn_k<0><<<WL1SZ, 512, 0, stream>>>(xb, w1t, H, list, wgt, basep, cnt, wl1);
  ffn_k<1><<<WL2SZ, 512, 0, stream>>>(H, w2t, out, list, wgt, basep, cnt, wl2);
}

// Round 8
// 386.664 us; speedup vs baseline: 1.5271x; 1.0272x over previous
//
#include <hip/hip_runtime.h>
#include <hip/hip_bf16.h>
#include <math.h>

// ExpertChoiceMoELayer: B=8,S=2048,D=1024,F=2048,E=8 -> T=16384, cap=2048
#define T_TOK 16384
#define DIM   1024
#define FF    2048
#define NE    8
#define CAPK  2048
#define MTE_MAX 16
#define WL1SZ (NE * 8 * MTE_MAX)  // 1024
#define WL2SZ (NE * 4 * MTE_MAX)  // 512

typedef unsigned short u16;
typedef unsigned long long u64;
typedef __attribute__((ext_vector_type(8))) short bf16x8;
typedef __attribute__((ext_vector_type(4))) float f32x4;

__device__ __forceinline__ u16 f2bf(float f) {
  __hip_bfloat16 h = __float2bfloat16(f);
  union { __hip_bfloat16 h; u16 u; } c; c.h = h; return c.u;
}

// fast GELU: 0.5x(1+erf(x/sqrt2)), erf via Abramowitz-Stegun 7.1.26 (|err|<=1.5e-7)
__device__ __forceinline__ float gelu_f(float v) {
  float z = fabsf(v) * 0.70710678118654752f;
  float t = __builtin_amdgcn_rcpf(1.0f + 0.3275911f * z);
  float poly = t * (0.254829592f +
               t * (-0.284496736f +
               t * (1.421413741f +
               t * (-1.453152027f +
               t * 1.061405429f))));
  float ez = __expf(-z * z);
  float erfz = 1.0f - poly * ez;
  erfz = copysignf(erfz, v);
  return 0.5f * v * (1.0f + erfz);
}

__device__ __forceinline__ void async_copy16(const void* g, void* l) {
  __builtin_amdgcn_global_load_lds(
      (const __attribute__((address_space(1))) unsigned int*)g,
      (__attribute__((address_space(3))) unsigned int*)l, 16, 0, 0);
}

// opaque LDS read: invisible to compiler waitcnt pass; ordering enforced by our
// volatile vmcnt/lgkmcnt/barrier asm + sched_barrier after each wait (rule #18)
__device__ __forceinline__ bf16x8 ds_read16(const char* p) {
  bf16x8 r;
  asm volatile("ds_read_b128 %0, %1"
               : "=&v"(r)
               : "v"((const __attribute__((address_space(3))) char*)p));
  return r;
}

// ---- merged weight transpose: fp32 [E][R][C] -> bf16 [E][C][R], 64x64 tiles ----
__global__ __launch_bounds__(256) void transpose_cvt2(const float* __restrict__ W1,
                                                      const float* __restrict__ W2,
                                                      u16* __restrict__ w1t,
                                                      u16* __restrict__ w2t) {
  __shared__ float tile[64][65];
  int z = blockIdx.y;
  const float* src;
  u16* dst;
  int R, C;
  if (z < 8) { src = W1 + (size_t)z * DIM * FF; dst = w1t + (size_t)z * DIM * FF; R = DIM; C = FF; }
  else       { src = W2 + (size_t)(z - 8) * FF * DIM; dst = w2t + (size_t)(z - 8) * FF * DIM; R = FF; C = DIM; }
  int nbx = C >> 6;
  int bx = blockIdx.x % nbx, by = blockIdx.x / nbx;
  int r0 = by * 64, c0 = bx * 64;
  int tid = threadIdx.x;
  int lr = tid >> 4, lc4 = (tid & 15) * 4;
#pragma unroll
  for (int p = 0; p < 4; ++p) {
    float4 v = *(const float4*)(src + (size_t)(r0 + p * 16 + lr) * C + c0 + lc4);
    tile[p * 16 + lr][lc4 + 0] = v.x;
    tile[p * 16 + lr][lc4 + 1] = v.y;
    tile[p * 16 + lr][lc4 + 2] = v.z;
    tile[p * 16 + lr][lc4 + 3] = v.w;
  }
  __syncthreads();
  int oc = tid >> 3, orr = (tid & 7) * 8;
#pragma unroll
  for (int p = 0; p < 2; ++p) {
    int c = p * 32 + oc;
    u16 h[8];
#pragma unroll
    for (int j = 0; j < 8; ++j) h[j] = f2bf(tile[orr + j][c]);
    *(uint4*)(dst + (size_t)(c0 + c) * R + r0 + orr) = *(uint4*)h;
  }
}

// ---- router: fp64-accum logits + softmax; probs [T][E], probsT [E][T], xb bf16;
//      also clears key/cnt/cnt2 (fused init) ----
__global__ __launch_bounds__(256) void router_k(const float* __restrict__ x,
                                                const float* __restrict__ Wg,
                                                float* __restrict__ probs,
                                                float* __restrict__ probsT,
                                                u16* __restrict__ xb,
                                                u64* __restrict__ key,
                                                int* cnt, int* cnt2) {
  int tid = threadIdx.x;
  if (tid < 4) key[blockIdx.x * 4 + tid] = 0ull;
  if (blockIdx.x == 0 && tid < NE) { cnt[tid] = 0; cnt2[tid] = 0; }
  int wid = tid >> 6, lane = tid & 63;
  int t = blockIdx.x * 4 + wid;
  const float* xr = x + (size_t)t * DIM;
  u16* xbr = xb + (size_t)t * DIM;
  double acc[NE] = {0, 0, 0, 0, 0, 0, 0, 0};
#pragma unroll 1
  for (int it = 0; it < DIM / 64; ++it) {
    int d = it * 64 + lane;
    float xv = xr[d];
    xbr[d] = f2bf(xv);
    const float4* wrow = (const float4*)(Wg + (size_t)d * NE);
    float4 w0 = wrow[0], w1 = wrow[1];
    acc[0] += (double)xv * (double)w0.x;
    acc[1] += (double)xv * (double)w0.y;
    acc[2] += (double)xv * (double)w0.z;
    acc[3] += (double)xv * (double)w0.w;
    acc[4] += (double)xv * (double)w1.x;
    acc[5] += (double)xv * (double)w1.y;
    acc[6] += (double)xv * (double)w1.z;
    acc[7] += (double)xv * (double)w1.w;
  }
#pragma unroll
  for (int e = 0; e < NE; ++e)
    for (int o = 32; o > 0; o >>= 1) acc[e] += __shfl_down(acc[e], o, 64);
  if (lane == 0) {
    float l[NE], mx = -3.0e38f;
#pragma unroll
    for (int e = 0; e < NE; ++e) { l[e] = (float)acc[e]; mx = fmaxf(mx, l[e]); }
    float s = 0.f;
#pragma unroll
    for (int e = 0; e < NE; ++e) { l[e] = expf(l[e] - mx); s += l[e]; }
    float inv = 1.0f / s;
#pragma unroll
    for (int e = 0; e < NE; ++e) {
      float p = l[e] * inv;
      probs[(size_t)t * NE + e] = p;
      probsT[(size_t)e * T_TOK + t] = p;
    }
  }
}

// ---- per-expert exact top-CAPK: 3-level radix (11/11/10 bits), per-wave L0 hist,
//      parallel shfl suffix/prefix scans ----
__global__ __launch_bounds__(256) void topk_sel(const float* __restrict__ probsT,
                                                u64* __restrict__ key) {
  __shared__ float pcol[T_TOK];          // 64 KB
  __shared__ unsigned whist[8][2048];    // 64 KB (level-0 per-wave)
  __shared__ unsigned hist[2048];        // 8 KB
  __shared__ unsigned bcast[2];
  __shared__ unsigned wsum[4];
  __shared__ int wps[4];
  int e = blockIdx.x, tid = threadIdx.x, wid = tid >> 6, lane = tid & 63;
  const float4* src4 = (const float4*)(probsT + (size_t)e * T_TOK);
  for (int i = tid; i < T_TOK / 4; i += 256) ((float4*)pcol)[i] = src4[i];
  for (int i = tid; i < 8 * 2048; i += 256) ((unsigned*)whist)[i] = 0;
  unsigned prefix = 0, remaining = CAPK;
#pragma unroll 1
  for (int lvl = 0; lvl < 3; ++lvl) {
    int nb = (lvl == 2) ? 1024 : 2048;
    if (lvl == 0) {
      __syncthreads();
      for (int i = tid; i < T_TOK; i += 256)
        atomicAdd(&whist[wid][__float_as_uint(pcol[i]) >> 21], 1u);
      __syncthreads();
      for (int j = tid; j < 2048; j += 256) {
        unsigned s2 = 0;
#pragma unroll
        for (int w = 0; w < 8; ++w) s2 += whist[w][j];
        hist[j] = s2;
      }
      __syncthreads();
    } else {
      for (int i = tid; i < 2048; i += 256) hist[i] = 0;
      __syncthreads();
      for (int i = tid; i < T_TOK; i += 256) {
        unsigned k = __float_as_uint(pcol[i]);
        bool m = (lvl == 1) ? ((k >> 21) == prefix) : ((k >> 10) == prefix);
        if (m) atomicAdd(&hist[(lvl == 1) ? ((k >> 10) & 2047u) : (k & 1023u)], 1u);
      }
      __syncthreads();
    }
    int nper = nb / 256;
    unsigned cv = 0;
    for (int j = 0; j < nper; ++j) cv += hist[tid * nper + j];
    unsigned s = cv;
#pragma unroll
    for (int o = 1; o < 64; o <<= 1) {
      unsigned tv = __shfl_down(s, o, 64);
      if (lane + o < 64) s += tv;
    }
    if (lane == 0) wsum[wid] = s;
    __syncthreads();
    unsigned above = 0;
    for (int w = wid + 1; w < 4; ++w) above += wsum[w];
    unsigned Sincl = s + above, Sexcl = Sincl - cv;
    if (Sincl >= remaining && Sexcl < remaining) {
      unsigned rem2 = remaining - Sexcl, cum2 = 0;
      for (int j = nper - 1; j >= 0; --j) {
        unsigned h = hist[tid * nper + j];
        if (cum2 + h >= rem2) { bcast[0] = (unsigned)(tid * nper + j); bcast[1] = rem2 - cum2; break; }
        cum2 += h;
      }
    }
    __syncthreads();
    unsigned b = bcast[0];
    remaining = bcast[1];
    prefix = (lvl == 0) ? b : (lvl == 1) ? ((prefix << 11) | b) : ((prefix << 10) | b);
    __syncthreads();
  }
  unsigned vk = prefix;
  int need = (int)remaining;
  const int CH = T_TOK / 256;
  int i0 = tid * CH;
  int myt = 0;
  for (int i = i0; i < i0 + CH; ++i)
    myt += (__float_as_uint(pcol[i]) == vk);
  int p = myt;
#pragma unroll
  for (int o = 1; o < 64; o <<= 1) {
    int tv = __shfl_up(p, o, 64);
    if (lane >= o) p += tv;
  }
  if (lane == 63) wps[wid] = p;
  __syncthreads();
  int wo = 0;
  for (int w = 0; w < wid; ++w) wo += wps[w];
  int run = wo + p - myt;
  u64 ebits = (u64)(7 - e);
  for (int i = i0; i < i0 + CH; ++i) {
    unsigned k = __float_as_uint(pcol[i]);
    bool sv = false;
    if (k > vk) sv = true;
    else if (k == vk) { if (run < need) sv = true; run++; }
    if (sv) atomicMax(&key[i], ((u64)k << 3) | ebits);
  }
}

__global__ __launch_bounds__(256) void assign_k(const float* __restrict__ probs,
                                                const u64* __restrict__ key,
                                                int* __restrict__ tok2exp,
                                                float* __restrict__ wgt, int* cnt) {
  int t = blockIdx.x * 256 + threadIdx.x;
  int lane = threadIdx.x & 63;
  u64 k = key[t];
  int best;
  float bp;
  if (k) {
    best = 7 - (int)(k & 7);
    bp = __uint_as_float((unsigned)(k >> 3));
  } else {
    best = 0; bp = -3.0e38f;
#pragma unroll
    for (int e = 0; e < NE; ++e) {
      float p = probs[(size_t)t * NE + e];
      if (p > bp) { bp = p; best = e; }
    }
  }
  tok2exp[t] = best;
  wgt[t] = bp;
#pragma unroll
  for (int e = 0; e < NE; ++e) {
    u64 m = __ballot(best == e);
    if (best == e && lane == __ffsll(m) - 1) atomicAdd(&cnt[e], (int)__popcll(m));
  }
}

// merged: basep + XCD-local worklists + slot compaction (wave-aggregated atomics)
__global__ __launch_bounds__(256) void slot_wl_k(const int* __restrict__ tok2exp,
                                                 const int* __restrict__ cnt,
                                                 int* cnt2, int* __restrict__ list,
                                                 int* basep, int* wl1, int* wl2) {
  int gid = blockIdx.x * 256 + threadIdx.x;
  int lane = threadIdx.x & 63;
  int c[NE];
#pragma unroll
  for (int e = 0; e < NE; ++e) c[e] = cnt[e];
  if (gid < NE) {
    int r = 0;
    for (int e = 0; e < gid; ++e) r += c[e];
    basep[gid] = r;
  }
  if (gid < WL1SZ) {
    int e = gid & 7, j = gid >> 3;
    int mte = (c[e] + 255) >> 8;
    int v = -1;
    if (j < 8 * mte) {
      int half = 4 * mte;
      int h = (j >= half) ? 1 : 0;
      int jj = j - h * half;
      v = e | ((jj >> 2) << 4) | (((h << 2) | (jj & 3)) << 12);
    }
    wl1[gid] = v;
  }
  if (gid >= WL1SZ && gid < WL1SZ + WL2SZ) {
    int g2 = gid - WL1SZ;
    int e = g2 & 7, j = g2 >> 3;
    int mte = (c[e] + 255) >> 8;
    int v = -1;
    if (j < 4 * mte) {
      int half = 2 * mte;
      int h = (j >= half) ? 1 : 0;
      int jj = j - h * half;
      v = e | ((jj >> 1) << 4) | (((h << 1) | (jj & 1)) << 12);
    }
    wl2[g2] = v;
  }
  int te = tok2exp[gid];
  int bp_e = 0;
#pragma unroll
  for (int e = 0; e < NE; ++e) if (e < te) bp_e += c[e];
  int sl = 0;
#pragma unroll
  for (int e = 0; e < NE; ++e) {
    u64 m = __ballot(te == e);
    if (te == e) {
      int leader = __ffsll(m) - 1;
      int rank = __popcll(m & ((1ull << lane) - 1));
      int b = 0;
      if (lane == leader) b = atomicAdd(&cnt2[e], (int)__popcll(m));
      b = __shfl(b, leader, 64);
      sl = bp_e + b + rank;
    }
  }
  list[sl] = gid;
}

// ============ grouped GEMM: 256x256 tile, BK=32, 4-deep ring, cross-phase ============
// pipelined LDS->reg with COUNTED lgkmcnt (ds latency hidden under MFMA),
// ONE barrier per K-tile, counted vmcnt (8/4/0), swizzled LDS, setprio
// EPI=0: H[slot] = GELU(xb[tok] @ W1t^T)   (K=DIM, N=FF)
// EPI=1: out[tok] = wgt * (H[slot] @ W2t^T) (K=FF,  N=DIM)

#define MF(M, N_, AV, BV) acc[M][N_] = __builtin_amdgcn_mfma_f32_16x16x32_bf16(BV, AV, acc[M][N_], 0, 0, 0)

#define SLOT_A(s) (sm + (s) * 32768)
#define SLOT_B(s) (sm + (s) * 32768 + 16384)

#define DSA_LO(s)                                                                 \
  pa = SLOT_A(s) + wr * 8192 + laneOff;                                           \
  a0 = ds_read16(pa);        a1 = ds_read16(pa + 1024);                           \
  a2 = ds_read16(pa + 2048); a3 = ds_read16(pa + 3072);

#define DSA_HI(s)                                                                 \
  pa = SLOT_A(s) + wr * 8192 + 4096 + laneOff;                                    \
  a4 = ds_read16(pa);        a5 = ds_read16(pa + 1024);                           \
  a6 = ds_read16(pa + 2048); a7 = ds_read16(pa + 3072);

#define DSB_RD(s, BP)                                                             \
  pb = SLOT_B(s) + wc * 4096 + laneOff;                                           \
  BP##0 = ds_read16(pb);        BP##1 = ds_read16(pb + 1024);                     \
  BP##2 = ds_read16(pb + 2048); BP##3 = ds_read16(pb + 3072);

#define LGKM(n)                                                                   \
  do {                                                                            \
    asm volatile("s_waitcnt lgkmcnt(" #n ")" ::: "memory");                       \
    __builtin_amdgcn_sched_barrier(0);                                            \
  } while (0)

#define VMW(n) asm volatile("s_waitcnt vmcnt(" #n ")" ::: "memory")
#define BAR() asm volatile("s_barrier" ::: "memory")

#define MFMA_LO(BP)                                                               \
  do {                                                                            \
    __builtin_amdgcn_s_setprio(1);                                                \
    MF(0, 0, a0, BP##0); MF(0, 1, a0, BP##1); MF(0, 2, a0, BP##2); MF(0, 3, a0, BP##3); \
    MF(1, 0, a1, BP##0); MF(1, 1, a1, BP##1); MF(1, 2, a1, BP##2); MF(1, 3, a1, BP##3); \
    MF(2, 0, a2, BP##0); MF(2, 1, a2, BP##1); MF(2, 2, a2, BP##2); MF(2, 3, a2, BP##3); \
    MF(3, 0, a3, BP##0); MF(3, 1, a3, BP##1); MF(3, 2, a3, BP##2); MF(3, 3, a3, BP##3); \
    __builtin_amdgcn_s_setprio(0);                                                \
  } while (0)

#define MFMA_HI(BP)                                                               \
  do {                                                                            \
    __builtin_amdgcn_s_setprio(1);                                                \
    MF(4, 0, a4, BP##0); MF(4, 1, a4, BP##1); MF(4, 2, a4, BP##2); MF(4, 3, a4, BP##3); \
    MF(5, 0, a5, BP##0); MF(5, 1, a5, BP##1); MF(5, 2, a5, BP##2); MF(5, 3, a5, BP##3); \
    MF(6, 0, a6, BP##0); MF(6, 1, a6, BP##1); MF(6, 2, a6, BP##2); MF(6, 3, a6, BP##3); \
    MF(7, 0, a7, BP##0); MF(7, 1, a7, BP##1); MF(7, 2, a7, BP##2); MF(7, 3, a7, BP##3); \
    __builtin_amdgcn_s_setprio(0);                                                \
  } while (0)

#define STAGE_A(s, kt)                                                            \
  do {                                                                            \
    async_copy16(aP0 + (size_t)(kt) * 64, SLOT_A(s) + wid * 1024);                \
    async_copy16(aP1 + (size_t)(kt) * 64, SLOT_A(s) + 8192 + wid * 1024);         \
  } while (0)

#define STAGE_B(s, kt)                                                            \
  do {                                                                            \
    async_copy16(bP0 + (size_t)(kt) * 64, SLOT_B(s) + wid * 1024);                \
    async_copy16(bP1 + (size_t)(kt) * 64, SLOT_B(s) + 8192 + wid * 1024);         \
  } while (0)

// One K-tile: ph0 {stageA(kt+3); read a-hi(kt); lgkm(4); MFMA-lo} then
// ph1 {stageB(kt+3); vmcnt; BAR; read B+a-lo of kt+1; lgkm(8); MFMA-hi}.
// Counted lgkm => LDS latency hides under the preceding MFMA cluster.
#define TILE_KT(kt, BCUR, BNXT)                                                   \
  do {                                                                            \
    const int sC = (kt) & 3, sP = ((kt) + 3) & 3, sN = ((kt) + 1) & 3;            \
    if ((kt) + 3 < KT) STAGE_A(sP, (kt) + 3);                                     \
    DSA_HI(sC);                                                                   \
    LGKM(4);                                                                      \
    MFMA_LO(BCUR);                                                                \
    if ((kt) + 3 < KT) STAGE_B(sP, (kt) + 3);                                     \
    if ((kt) < KT - 1) {                                                          \
      if ((kt) < KT - 3)        { VMW(8); }                                       \
      else if ((kt) == KT - 3)  { VMW(4); }                                       \
      else                      { VMW(0); }                                       \
      BAR();                                                                      \
      DSB_RD(sN, BNXT);                                                           \
      DSA_LO(sN);                                                                 \
      LGKM(8);                                                                    \
    } else {                                                                      \
      LGKM(0);                                                                    \
    }                                                                             \
    MFMA_HI(BCUR);                                                                \
  } while (0)

template <int EPI>
__global__ __launch_bounds__(512, 2) void ffn_k(const u16* __restrict__ A,
                                                const u16* __restrict__ Bm,
                                                void* __restrict__ Out,
                                                const int* __restrict__ list,
                                                const float* __restrict__ wgt,
                                                const int* __restrict__ basep,
                                                const int* __restrict__ cnt,
                                                const int* __restrict__ wl) {
  constexpr int K = EPI ? FF : DIM;
  constexpr int N = EPI ? DIM : FF;
  constexpr int KT = K / 32;

  const int wle = wl[blockIdx.x];
  if (wle < 0) return;
  const int e = wle & 15, mt = (wle >> 4) & 255, nt = wle >> 12;
  const int ce = cnt[e];
  const int be = basep[e];

  __shared__ u16 smem[65536];   // 128 KiB: 4 ring slots x (A 16KB + B 16KB)
  __shared__ int toks[256];
  __shared__ float wsc[256];
  char* const sm = (char*)smem;

  const int tid = threadIdx.x;
  if (tid < 256) {
    int r = mt * 256 + tid;
    int tk = (r < ce) ? list[be + r] : list[be];
    toks[tid] = tk;
    if (EPI == 1) wsc[tid] = wgt[tk];
  }
  __syncthreads();

  const int wid = tid >> 6, lane = tid & 63;
  const int wr = wid >> 2, wc = wid & 3;
  // swizzled per-lane frag-read offset (2 rows per 128B line, XOR on line&3)
  const int laneOff = ((lane & 15) >> 1) * 128 + (lane & 1) * 64 +
                      (((lane >> 4) << 4) ^ (((lane >> 1) & 3) << 4));

  // staging: thread covers tile rows tr0 (call 0) and tr1=tr0+128 (call 1)
  const int tr0 = ((tid >> 3) << 1) + ((tid >> 2) & 1), tr1 = 128 + tr0;
  const int cbl = ((tid & 3) << 4) ^ (((tid >> 3) & 3) << 4);
  const char *aP0, *aP1;
  if (EPI == 0) {
    aP0 = (const char*)(A + (size_t)toks[tr0] * K) + cbl;
    aP1 = (const char*)(A + (size_t)toks[tr1] * K) + cbl;
  } else {
    aP0 = (const char*)(A + ((size_t)be + mt * 256 + tr0) * K) + cbl;
    aP1 = (const char*)(A + ((size_t)be + mt * 256 + tr1) * K) + cbl;
  }
  const char* bP0 = (const char*)(Bm + ((size_t)e * N + nt * 256 + tr0) * K) + cbl;
  const char* bP1 = (const char*)(Bm + ((size_t)e * N + nt * 256 + tr1) * K) + cbl;

  f32x4 acc[8][4];
#pragma unroll
  for (int m = 0; m < 8; ++m)
#pragma unroll
    for (int n = 0; n < 4; ++n) acc[m][n] = (f32x4){0.f, 0.f, 0.f, 0.f};

  // prologue: stage slots 0,1,2 (3 K-tiles ahead = 12 loads)
  STAGE_A(0, 0); STAGE_B(0, 0);
  STAGE_A(1, 1); STAGE_B(1, 1);
  STAGE_A(2, 2); STAGE_B(2, 2);
  VMW(8);   // tile 0 landed
  BAR();

  const char* pa;
  const char* pb;
  bf16x8 a0, a1, a2, a3, a4, a5, a6, a7;
  bf16x8 bA0, bA1, bA2, bA3, bB0, bB1, bB2, bB3;

  // prime: B(t0) + A-lo(t0); drained by first tile's LGKM(4)
  DSB_RD(0, bA);
  DSA_LO(0);

#pragma unroll 1
  for (int kt = 0; kt < KT; kt += 2) {
    TILE_KT(kt, bA, bB);
    TILE_KT(kt + 1, bB, bA);
  }

  // epilogue: operand-swap => acc reg index runs along output cols -> vector stores
  const int lc = lane & 15, lq = (lane >> 4) * 4;
#pragma unroll
  for (int m = 0; m < 8; ++m) {
    int trow = wr * 128 + m * 16 + lc;
    int grow = mt * 256 + trow;
    if (grow < ce) {
      if (EPI == 0) {
        size_t rowoff = (size_t)(be + grow) * FF + nt * 256 + wc * 64 + lq;
#pragma unroll
        for (int n = 0; n < 4; ++n) {
          ushort4 h4;
          h4.x = f2bf(gelu_f(acc[m][n][0]));
          h4.y = f2bf(gelu_f(acc[m][n][1]));
          h4.z = f2bf(gelu_f(acc[m][n][2]));
          h4.w = f2bf(gelu_f(acc[m][n][3]));
          *(ushort4*)((u16*)Out + rowoff + n * 16) = h4;
        }
      } else {
        float w = wsc[trow];
        size_t rowoff = (size_t)toks[trow] * DIM + nt * 256 + wc * 64 + lq;
#pragma unroll
        for (int n = 0; n < 4; ++n) {
          float4 o = make_float4(w * acc[m][n][0], w * acc[m][n][1],
                                 w * acc[m][n][2], w * acc[m][n][3]);
          *(float4*)((float*)Out + rowoff + n * 16) = o;
        }
      }
    }
  }
}

extern "C" void kernel_launch(void* const* d_in, const int* in_sizes, int n_in,
                              void* d_out, int out_size, void* d_ws, size_t ws_size,
                              hipStream_t stream) {
  (void)in_sizes; (void)n_in; (void)out_size; (void)ws_size;
  const float* x  = (const float*)d_in[0];
  const float* Wg = (const float*)d_in[1];
  const float* W1 = (const float*)d_in[2];
  const float* W2 = (const float*)d_in[3];
  float* out = (float*)d_out;

  char* ws = (char*)d_ws;
  size_t off = 0;
  auto alloc = [&](size_t bytes) -> void* {
    void* p = ws + off;
    off += (bytes + 255) & ~(size_t)255;
    return p;
  };
  u16* xb   = (u16*)alloc((size_t)T_TOK * DIM * 2);         // 32 MB (token-order bf16 x)
  u16* w1t  = (u16*)alloc((size_t)NE * FF * DIM * 2);       // 32 MB  [E][F][D]
  u16* w2t  = (u16*)alloc((size_t)NE * DIM * FF * 2);       // 32 MB  [E][D][F]
  u16* H    = (u16*)alloc((size_t)(T_TOK + 256) * FF * 2);  // 65 MB, padded
  float* probs  = (float*)alloc((size_t)T_TOK * NE * 4);
  float* probsT = (float*)alloc((size_t)NE * T_TOK * 4);
  u64* key      = (u64*)alloc((size_t)T_TOK * 8);
  float* wgt    = (float*)alloc((size_t)T_TOK * 4);
  int* tok2exp  = (int*)alloc((size_t)T_TOK * 4);
  int* list     = (int*)alloc((size_t)T_TOK * 4);
  int* cnt      = (int*)alloc(64);
  int* cnt2     = (int*)alloc(64);
  int* basep    = (int*)alloc(64);
  int* wl1      = (int*)alloc(WL1SZ * 4);
  int* wl2      = (int*)alloc(WL2SZ * 4);

  transpose_cvt2<<<dim3(512, 16), 256, 0, stream>>>(W1, W2, w1t, w2t);
  router_k<<<T_TOK / 4, 256, 0, stream>>>(x, Wg, probs, probsT, xb, key, cnt, cnt2);
  topk_sel<<<NE, 256, 0, stream>>>(probsT, key);
  assign_k<<<T_TOK / 256, 256, 0, stream>>>(probs, key, tok2exp, wgt, cnt);
  slot_wl_k<<<T_TOK / 256, 256, 0, stream>>>(tok2exp, cnt, cnt2, list, basep, wl1, wl2);
  ffn_k<0><<<WL1SZ, 512, 0, stream>>>(xb, w1t, H, list, wgt, basep, cnt, wl1);
  ffn_k<1><<<WL2SZ, 512, 0, stream>>>(H, w2t, out, list, wgt, basep, cnt, wl2);
}

// Round 9
// 376.709 us; speedup vs baseline: 1.5675x; 1.0264x over previous
//
#include <hip/hip_runtime.h>
#include <hip/hip_bf16.h>
#include <math.h>

// ExpertChoiceMoELayer: B=8,S=2048,D=1024,F=2048,E=8 -> T=16384, cap=2048
#define T_TOK 16384
#define DIM   1024
#define FF    2048
#define NE    8
#define CAPK  2048
#define WL1SZ 4096   // 8 experts x 512 (mt<=32 x nt16) 128-row tiles
#define WL2SZ 2048   // 8 experts x 256 (mt<=32 x nt8)

typedef unsigned short u16;
typedef unsigned long long u64;
typedef __attribute__((ext_vector_type(8))) short bf16x8;
typedef __attribute__((ext_vector_type(4))) float f32x4;

__device__ __forceinline__ u16 f2bf(float f) {
  __hip_bfloat16 h = __float2bfloat16(f);
  union { __hip_bfloat16 h; u16 u; } c; c.h = h; return c.u;
}

// fast GELU: 0.5x(1+erf(x/sqrt2)), erf via Abramowitz-Stegun 7.1.26 (|err|<=1.5e-7)
__device__ __forceinline__ float gelu_f(float v) {
  float z = fabsf(v) * 0.70710678118654752f;
  float t = __builtin_amdgcn_rcpf(1.0f + 0.3275911f * z);
  float poly = t * (0.254829592f +
               t * (-0.284496736f +
               t * (1.421413741f +
               t * (-1.453152027f +
               t * 1.061405429f))));
  float ez = __expf(-z * z);
  float erfz = 1.0f - poly * ez;
  erfz = copysignf(erfz, v);
  return 0.5f * v * (1.0f + erfz);
}

__device__ __forceinline__ void async_copy16(const void* g, void* l) {
  __builtin_amdgcn_global_load_lds(
      (const __attribute__((address_space(1))) unsigned int*)g,
      (__attribute__((address_space(3))) unsigned int*)l, 16, 0, 0);
}

// opaque LDS read (rule #18 discipline): ordering enforced by our asm waits
__device__ __forceinline__ bf16x8 ds_read16(const char* p) {
  bf16x8 r;
  asm volatile("ds_read_b128 %0, %1"
               : "=&v"(r)
               : "v"((const __attribute__((address_space(3))) char*)p));
  return r;
}

#define LGKM0()                                                                   \
  do {                                                                            \
    asm volatile("s_waitcnt lgkmcnt(0)" ::: "memory");                            \
    __builtin_amdgcn_sched_barrier(0);                                            \
  } while (0)
#define VMW0() asm volatile("s_waitcnt vmcnt(0)" ::: "memory")
#define BAR() asm volatile("s_barrier" ::: "memory")

// ===== K1: merged router (bid<4096) + weight transpose (bid>=4096) =====
__global__ __launch_bounds__(256) void prep_k(const float* __restrict__ x,
                                              const float* __restrict__ Wg,
                                              const float* __restrict__ W1,
                                              const float* __restrict__ W2,
                                              float* __restrict__ probs,
                                              float* __restrict__ probsT,
                                              u16* __restrict__ xb,
                                              u16* __restrict__ w1t,
                                              u16* __restrict__ w2t,
                                              u64* __restrict__ key,
                                              int* cnt, int* cnt2, int* gates) {
  __shared__ float tile[64][65];
  int bid = blockIdx.x, tid = threadIdx.x;
  if (bid < 4096) {
    // ---- router: fp64-accum logits + softmax; also zero key/cnt/gates ----
    if (tid < 4) key[bid * 4 + tid] = 0ull;
    if (bid == 0 && tid < NE) { cnt[tid] = 0; cnt2[tid] = 0; }
    if (bid == 0 && tid >= 8 && tid < 10) gates[tid - 8] = 0;
    int wid = tid >> 6, lane = tid & 63;
    int t = bid * 4 + wid;
    const float* xr = x + (size_t)t * DIM;
    u16* xbr = xb + (size_t)t * DIM;
    double acc[NE] = {0, 0, 0, 0, 0, 0, 0, 0};
#pragma unroll 1
    for (int it = 0; it < DIM / 64; ++it) {
      int d = it * 64 + lane;
      float xv = xr[d];
      xbr[d] = f2bf(xv);
      const float4* wrow = (const float4*)(Wg + (size_t)d * NE);
      float4 w0 = wrow[0], w1 = wrow[1];
      acc[0] += (double)xv * (double)w0.x;
      acc[1] += (double)xv * (double)w0.y;
      acc[2] += (double)xv * (double)w0.z;
      acc[3] += (double)xv * (double)w0.w;
      acc[4] += (double)xv * (double)w1.x;
      acc[5] += (double)xv * (double)w1.y;
      acc[6] += (double)xv * (double)w1.z;
      acc[7] += (double)xv * (double)w1.w;
    }
#pragma unroll
    for (int e = 0; e < NE; ++e)
      for (int o = 32; o > 0; o >>= 1) acc[e] += __shfl_down(acc[e], o, 64);
    if (lane == 0) {
      float l[NE], mx = -3.0e38f;
#pragma unroll
      for (int e = 0; e < NE; ++e) { l[e] = (float)acc[e]; mx = fmaxf(mx, l[e]); }
      float s = 0.f;
#pragma unroll
      for (int e = 0; e < NE; ++e) { l[e] = expf(l[e] - mx); s += l[e]; }
      float inv = 1.0f / s;
#pragma unroll
      for (int e = 0; e < NE; ++e) {
        float p = l[e] * inv;
        probs[(size_t)t * NE + e] = p;
        probsT[(size_t)e * T_TOK + t] = p;
      }
    }
  } else {
    // ---- weight transpose: fp32 [E][R][C] -> bf16 [E][C][R], 64x64 tiles ----
    int tz = bid - 4096;            // 0..8191
    int z = tz >> 9, bxy = tz & 511;
    const float* src;
    u16* dst;
    int R, C;
    if (z < 8) { src = W1 + (size_t)z * DIM * FF; dst = w1t + (size_t)z * DIM * FF; R = DIM; C = FF; }
    else       { src = W2 + (size_t)(z - 8) * FF * DIM; dst = w2t + (size_t)(z - 8) * FF * DIM; R = FF; C = DIM; }
    int nbx = C >> 6;
    int bx = bxy % nbx, by = bxy / nbx;
    int r0 = by * 64, c0 = bx * 64;
    int lr = tid >> 4, lc4 = (tid & 15) * 4;
#pragma unroll
    for (int p = 0; p < 4; ++p) {
      float4 v = *(const float4*)(src + (size_t)(r0 + p * 16 + lr) * C + c0 + lc4);
      tile[p * 16 + lr][lc4 + 0] = v.x;
      tile[p * 16 + lr][lc4 + 1] = v.y;
      tile[p * 16 + lr][lc4 + 2] = v.z;
      tile[p * 16 + lr][lc4 + 3] = v.w;
    }
    __syncthreads();
    int oc = tid >> 3, orr = (tid & 7) * 8;
#pragma unroll
    for (int p = 0; p < 2; ++p) {
      int c = p * 32 + oc;
      u16 h[8];
#pragma unroll
      for (int j = 0; j < 8; ++j) h[j] = f2bf(tile[orr + j][c]);
      *(uint4*)(dst + (size_t)(c0 + c) * R + r0 + orr) = *(uint4*)h;
    }
  }
}

// ===== K2: merged topk(8 blocks) + assign(64) + slot/wl(64) via atomic gates =====
// All 136 blocks co-resident (<=256 CUs) -> spin-waits are deadlock-free.
__global__ __launch_bounds__(256) void moe_route_k(const float* __restrict__ probsT,
                                                   const float* __restrict__ probs,
                                                   u64* __restrict__ key,
                                                   int* __restrict__ tok2exp,
                                                   float* __restrict__ wgt,
                                                   int* cnt, int* cnt2,
                                                   int* __restrict__ list,
                                                   int* basep, int* wl1, int* wl2,
                                                   int* gates) {
  __shared__ float pcol[T_TOK];          // 64 KB (topk blocks only)
  __shared__ unsigned whist[8][2048];    // 64 KB
  __shared__ unsigned hist[2048];
  __shared__ unsigned bcast[2];
  __shared__ unsigned wsum[4];
  __shared__ int wps[4];
  int bid = blockIdx.x, tid = threadIdx.x, wid = tid >> 6, lane = tid & 63;
  if (bid < 8) {
    // ---- topk: 3-level radix (11/11/10), per-wave L0 hist, shfl scans ----
    int e = bid;
    const float4* src4 = (const float4*)(probsT + (size_t)e * T_TOK);
    for (int i = tid; i < T_TOK / 4; i += 256) ((float4*)pcol)[i] = src4[i];
    for (int i = tid; i < 8 * 2048; i += 256) ((unsigned*)whist)[i] = 0;
    unsigned prefix = 0, remaining = CAPK;
#pragma unroll 1
    for (int lvl = 0; lvl < 3; ++lvl) {
      int nb = (lvl == 2) ? 1024 : 2048;
      if (lvl == 0) {
        __syncthreads();
        for (int i = tid; i < T_TOK; i += 256)
          atomicAdd(&whist[wid][__float_as_uint(pcol[i]) >> 21], 1u);
        __syncthreads();
        for (int j = tid; j < 2048; j += 256) {
          unsigned s2 = 0;
#pragma unroll
          for (int w = 0; w < 8; ++w) s2 += whist[w][j];
          hist[j] = s2;
        }
        __syncthreads();
      } else {
        for (int i = tid; i < 2048; i += 256) hist[i] = 0;
        __syncthreads();
        for (int i = tid; i < T_TOK; i += 256) {
          unsigned k = __float_as_uint(pcol[i]);
          bool m = (lvl == 1) ? ((k >> 21) == prefix) : ((k >> 10) == prefix);
          if (m) atomicAdd(&hist[(lvl == 1) ? ((k >> 10) & 2047u) : (k & 1023u)], 1u);
        }
        __syncthreads();
      }
      int nper = nb / 256;
      unsigned cv = 0;
      for (int j = 0; j < nper; ++j) cv += hist[tid * nper + j];
      unsigned s = cv;
#pragma unroll
      for (int o = 1; o < 64; o <<= 1) {
        unsigned tv = __shfl_down(s, o, 64);
        if (lane + o < 64) s += tv;
      }
      if (lane == 0) wsum[wid] = s;
      __syncthreads();
      unsigned above = 0;
      for (int w = wid + 1; w < 4; ++w) above += wsum[w];
      unsigned Sincl = s + above, Sexcl = Sincl - cv;
      if (Sincl >= remaining && Sexcl < remaining) {
        unsigned rem2 = remaining - Sexcl, cum2 = 0;
        for (int j = nper - 1; j >= 0; --j) {
          unsigned h = hist[tid * nper + j];
          if (cum2 + h >= rem2) { bcast[0] = (unsigned)(tid * nper + j); bcast[1] = rem2 - cum2; break; }
          cum2 += h;
        }
      }
      __syncthreads();
      unsigned b = bcast[0];
      remaining = bcast[1];
      prefix = (lvl == 0) ? b : (lvl == 1) ? ((prefix << 11) | b) : ((prefix << 10) | b);
      __syncthreads();
    }
    unsigned vk = prefix;
    int need = (int)remaining;
    const int CH = T_TOK / 256;
    int i0 = tid * CH;
    int myt = 0;
    for (int i = i0; i < i0 + CH; ++i)
      myt += (__float_as_uint(pcol[i]) == vk);
    int p = myt;
#pragma unroll
    for (int o = 1; o < 64; o <<= 1) {
      int tv = __shfl_up(p, o, 64);
      if (lane >= o) p += tv;
    }
    if (lane == 63) wps[wid] = p;
    __syncthreads();
    int wo = 0;
    for (int w = 0; w < wid; ++w) wo += wps[w];
    int run = wo + p - myt;
    u64 ebits = (u64)(7 - e);
    for (int i = i0; i < i0 + CH; ++i) {
      unsigned k = __float_as_uint(pcol[i]);
      bool sv = false;
      if (k > vk) sv = true;
      else if (k == vk) { if (run < need) sv = true; run++; }
      if (sv) atomicMax(&key[i], ((u64)k << 3) | ebits);
    }
    __threadfence();
    __syncthreads();
    if (tid == 0) atomicAdd(&gates[0], 1);
  } else if (bid < 72) {
    // ---- assign: wait for all 8 topk blocks ----
    if (tid == 0) {
      while (atomicAdd(&gates[0], 0) < 8) __builtin_amdgcn_s_sleep(8);
    }
    __syncthreads();
    __threadfence();
    int t = (bid - 8) * 256 + tid;
    u64 k = key[t];
    int best;
    float bp;
    if (k) {
      best = 7 - (int)(k & 7);
      bp = __uint_as_float((unsigned)(k >> 3));
    } else {
      best = 0; bp = -3.0e38f;
#pragma unroll
      for (int e = 0; e < NE; ++e) {
        float p = probs[(size_t)t * NE + e];
        if (p > bp) { bp = p; best = e; }
      }
    }
    tok2exp[t] = best;
    wgt[t] = bp;
#pragma unroll
    for (int e = 0; e < NE; ++e) {
      u64 m = __ballot(best == e);
      if (best == e && lane == __ffsll(m) - 1) atomicAdd(&cnt[e], (int)__popcll(m));
    }
    __threadfence();
    __syncthreads();
    if (tid == 0) atomicAdd(&gates[1], 1);
  } else {
    // ---- slot compaction + basep + worklists: wait for all 64 assign blocks ----
    if (tid == 0) {
      while (atomicAdd(&gates[1], 0) < 64) __builtin_amdgcn_s_sleep(8);
    }
    __syncthreads();
    __threadfence();
    int gid = (bid - 72) * 256 + tid;
    int c[NE];
#pragma unroll
    for (int e = 0; e < NE; ++e) c[e] = cnt[e];
    if (gid < NE) {
      int r = 0;
      for (int e = 0; e < gid; ++e) r += c[e];
      basep[gid] = r;
    }
    if (gid < WL1SZ) {
      int e = gid & 7, j = gid >> 3;      // j 0..511
      int mte = (c[e] + 127) >> 7;
      wl1[gid] = (j < mte * 16) ? (e | ((j >> 4) << 4) | ((j & 15) << 12)) : -1;
    }
    if (gid >= WL1SZ && gid < WL1SZ + WL2SZ) {
      int g2 = gid - WL1SZ;
      int e = g2 & 7, j = g2 >> 3;        // j 0..255
      int mte = (c[e] + 127) >> 7;
      wl2[g2] = (j < mte * 8) ? (e | ((j >> 3) << 4) | ((j & 7) << 12)) : -1;
    }
    int te = tok2exp[gid];
    int bp_e = 0;
#pragma unroll
    for (int e = 0; e < NE; ++e) if (e < te) bp_e += c[e];
    int sl = 0;
#pragma unroll
    for (int e = 0; e < NE; ++e) {
      u64 m = __ballot(te == e);
      if (te == e) {
        int leader = __ffsll(m) - 1;
        int rank = __popcll(m & ((1ull << lane) - 1));
        int b = 0;
        if (lane == leader) b = atomicAdd(&cnt2[e], (int)__popcll(m));
        b = __shfl(b, leader, 64);
        sl = bp_e + b + rank;
      }
    }
    list[sl] = gid;
  }
}

// ===== FFN: 128x128 tile, BK=64, 256 thr (4 waves 2x2), double-buffered 64KB =====
// -> 2 blocks/CU (cross-block latency hiding, m114), 1 barrier/tile, asm ds_read,
// swizzled LDS, setprio, operand-swapped MFMA.
// EPI=0: H[slot] = GELU(xb[tok] @ W1t^T)   (K=DIM, N=FF)
// EPI=1: out[tok] = wgt * (H[slot] @ W2t^T) (K=FF,  N=DIM)

#define MF(M, N_, AV, BV) acc[M][N_] = __builtin_amdgcn_mfma_f32_16x16x32_bf16(BV, AV, acc[M][N_], 0, 0, 0)

#define STG(b, kt)                                                                \
  do {                                                                            \
    char* dA = sm + (b) * 32768;                                                  \
    char* dB = dA + 16384;                                                        \
    size_t ko = (size_t)(kt) * 128;                                               \
    async_copy16(aP0 + ko,      dA + tid * 16);                                   \
    async_copy16(aP1 + ko,      dA + 4096 + tid * 16);                            \
    async_copy16(aP0 + ko + 64, dA + 8192 + tid * 16);                            \
    async_copy16(aP1 + ko + 64, dA + 12288 + tid * 16);                           \
    async_copy16(bP0 + ko,      dB + tid * 16);                                   \
    async_copy16(bP1 + ko,      dB + 4096 + tid * 16);                            \
    async_copy16(bP0 + ko + 64, dB + 8192 + tid * 16);                            \
    async_copy16(bP1 + ko + 64, dB + 12288 + tid * 16);                           \
  } while (0)

#define DSRD(kkoff)                                                               \
  do {                                                                            \
    const char* pa = sm + bb * 32768 + (kkoff) + wr * 4096 + laneOff;             \
    const char* pb = sm + bb * 32768 + 16384 + (kkoff) + wc * 4096 + laneOff;     \
    a0 = ds_read16(pa);        a1 = ds_read16(pa + 1024);                         \
    a2 = ds_read16(pa + 2048); a3 = ds_read16(pa + 3072);                         \
    b0 = ds_read16(pb);        b1 = ds_read16(pb + 1024);                         \
    b2 = ds_read16(pb + 2048); b3 = ds_read16(pb + 3072);                         \
  } while (0)

#define MFMA16()                                                                  \
  do {                                                                            \
    __builtin_amdgcn_s_setprio(1);                                                \
    MF(0, 0, a0, b0); MF(0, 1, a0, b1); MF(0, 2, a0, b2); MF(0, 3, a0, b3);       \
    MF(1, 0, a1, b0); MF(1, 1, a1, b1); MF(1, 2, a1, b2); MF(1, 3, a1, b3);       \
    MF(2, 0, a2, b0); MF(2, 1, a2, b1); MF(2, 2, a2, b2); MF(2, 3, a2, b3);       \
    MF(3, 0, a3, b0); MF(3, 1, a3, b1); MF(3, 2, a3, b2); MF(3, 3, a3, b3);       \
    __builtin_amdgcn_s_setprio(0);                                                \
  } while (0)

template <int EPI>
__global__ __launch_bounds__(256, 2) void ffn_k(const u16* __restrict__ A,
                                                const u16* __restrict__ Bm,
                                                void* __restrict__ Out,
                                                const int* __restrict__ list,
                                                const float* __restrict__ wgt,
                                                const int* __restrict__ basep,
                                                const int* __restrict__ cnt,
                                                const int* __restrict__ wl) {
  constexpr int K = EPI ? FF : DIM;
  constexpr int N = EPI ? DIM : FF;
  constexpr int KT = K / 64;

  const int wle = wl[blockIdx.x];
  if (wle < 0) return;
  const int e = wle & 15, mt = (wle >> 4) & 255, nt = wle >> 12;
  const int ce = cnt[e];
  const int be = basep[e];

  __shared__ u16 smem[32768];   // 64 KiB: 2 bufs x (A 16KB + B 16KB)
  __shared__ int toks[128];
  __shared__ float wsc[128];
  char* const sm = (char*)smem;

  const int tid = threadIdx.x;
  if (tid < 128) {
    int r = mt * 128 + tid;
    int tk = (r < ce) ? list[be + r] : list[be];
    toks[tid] = tk;
    if (EPI == 1) wsc[tid] = wgt[tk];
  }
  __syncthreads();

  const int wid = tid >> 6, lane = tid & 63;
  const int wr = wid >> 1, wc = wid & 1;
  // swizzled frag-read offset (2 rows per 128B line, XOR on line&3) — verified R4-R8
  const int laneOff = ((lane & 15) >> 1) * 128 + (lane & 1) * 64 +
                      (((lane >> 4) << 4) ^ ((((lane & 15) >> 1) & 3) << 4));

  // staging: thread covers rows r0 and r0+64; inverse-swizzled source column
  const int r0 = 2 * (tid >> 3) + ((tid & 7) >> 2);     // 0..63
  const int cbl = ((tid & 3) << 4) ^ (((tid >> 3) & 3) << 4);
  const char *aP0, *aP1;
  if (EPI == 0) {
    aP0 = (const char*)(A + (size_t)toks[r0] * K) + cbl;
    aP1 = (const char*)(A + (size_t)toks[r0 + 64] * K) + cbl;
  } else {
    aP0 = (const char*)(A + ((size_t)be + mt * 128 + r0) * K) + cbl;
    aP1 = (const char*)(A + ((size_t)be + mt * 128 + r0 + 64) * K) + cbl;
  }
  const char* bP0 = (const char*)(Bm + ((size_t)e * N + nt * 128 + r0) * K) + cbl;
  const char* bP1 = (const char*)(Bm + ((size_t)e * N + nt * 128 + r0 + 64) * K) + cbl;

  f32x4 acc[4][4];
#pragma unroll
  for (int m = 0; m < 4; ++m)
#pragma unroll
    for (int n = 0; n < 4; ++n) acc[m][n] = (f32x4){0.f, 0.f, 0.f, 0.f};

  // prologue
  STG(0, 0);
  VMW0();
  BAR();

  bf16x8 a0, a1, a2, a3, b0, b1, b2, b3;

#pragma unroll 1
  for (int kt = 0; kt < KT; ++kt) {
    const int bb = kt & 1;
    if (kt + 1 < KT) STG(bb ^ 1, kt + 1);   // prefetch next tile into other buf
    DSRD(0);                                // kk0 frags
    LGKM0();
    MFMA16();
    DSRD(8192);                             // kk1 frags
    LGKM0();
    MFMA16();
    VMW0();                                 // own prefetch landed (covered by compute)
    BAR();                                  // all waves done reading + staging visible
  }

  // epilogue: operand-swap => acc reg index runs along output cols -> vector stores
  const int lc = lane & 15, lq = (lane >> 4) * 4;
#pragma unroll
  for (int m = 0; m < 4; ++m) {
    int trow = wr * 64 + m * 16 + lc;
    int grow = mt * 128 + trow;
    if (grow < ce) {
      if (EPI == 0) {
        size_t rowoff = (size_t)(be + grow) * FF + nt * 128 + wc * 64 + lq;
#pragma unroll
        for (int n = 0; n < 4; ++n) {
          ushort4 h4;
          h4.x = f2bf(gelu_f(acc[m][n][0]));
          h4.y = f2bf(gelu_f(acc[m][n][1]));
          h4.z = f2bf(gelu_f(acc[m][n][2]));
          h4.w = f2bf(gelu_f(acc[m][n][3]));
          *(ushort4*)((u16*)Out + rowoff + n * 16) = h4;
        }
      } else {
        float w = wsc[trow];
        size_t rowoff = (size_t)toks[trow] * DIM + nt * 128 + wc * 64 + lq;
#pragma unroll
        for (int n = 0; n < 4; ++n) {
          float4 o = make_float4(w * acc[m][n][0], w * acc[m][n][1],
                                 w * acc[m][n][2], w * acc[m][n][3]);
          *(float4*)((float*)Out + rowoff + n * 16) = o;
        }
      }
    }
  }
}

extern "C" void kernel_launch(void* const* d_in, const int* in_sizes, int n_in,
                              void* d_out, int out_size, void* d_ws, size_t ws_size,
                              hipStream_t stream) {
  (void)in_sizes; (void)n_in; (void)out_size; (void)ws_size;
  const float* x  = (const float*)d_in[0];
  const float* Wg = (const float*)d_in[1];
  const float* W1 = (const float*)d_in[2];
  const float* W2 = (const float*)d_in[3];
  float* out = (float*)d_out;

  char* ws = (char*)d_ws;
  size_t off = 0;
  auto alloc = [&](size_t bytes) -> void* {
    void* p = ws + off;
    off += (bytes + 255) & ~(size_t)255;
    return p;
  };
  u16* xb   = (u16*)alloc((size_t)T_TOK * DIM * 2);         // 32 MB
  u16* w1t  = (u16*)alloc((size_t)NE * FF * DIM * 2);       // 32 MB  [E][F][D]
  u16* w2t  = (u16*)alloc((size_t)NE * DIM * FF * 2);       // 32 MB  [E][D][F]
  u16* H    = (u16*)alloc((size_t)(T_TOK + 256) * FF * 2);  // 65 MB, padded
  float* probs  = (float*)alloc((size_t)T_TOK * NE * 4);
  float* probsT = (float*)alloc((size_t)NE * T_TOK * 4);
  u64* key      = (u64*)alloc((size_t)T_TOK * 8);
  float* wgt    = (float*)alloc((size_t)T_TOK * 4);
  int* tok2exp  = (int*)alloc((size_t)T_TOK * 4);
  int* list     = (int*)alloc((size_t)T_TOK * 4);
  int* cnt      = (int*)alloc(64);
  int* cnt2     = (int*)alloc(64);
  int* basep    = (int*)alloc(64);
  int* gates    = (int*)alloc(64);
  int* wl1      = (int*)alloc(WL1SZ * 4);
  int* wl2      = (int*)alloc(WL2SZ * 4);

  prep_k<<<4096 + 8192, 256, 0, stream>>>(x, Wg, W1, W2, probs, probsT, xb, w1t, w2t,
                                          key, cnt, cnt2, gates);
  moe_route_k<<<136, 256, 0, stream>>>(probsT, probs, key, tok2exp, wgt, cnt, cnt2,
                                       list, basep, wl1, wl2, gates);
  ffn_k<0><<<WL1SZ, 256, 0, stream>>>(xb, w1t, H, list, wgt, basep, cnt, wl1);
  ffn_k<1><<<WL2SZ, 256, 0, stream>>>(H, w2t, out, list, wgt, basep, cnt, wl2);
}

// Round 10
// 358.199 us; speedup vs baseline: 1.6485x; 1.0517x over previous
//
#include <hip/hip_runtime.h>
#include <hip/hip_bf16.h>
#include <math.h>

// ExpertChoiceMoELayer: B=8,S=2048,D=1024,F=2048,E=8 -> T=16384, cap=2048
#define T_TOK 16384
#define DIM   1024
#define FF    2048
#define NE    8
#define CAPK  2048
#define WL1SZ 4096   // 8 experts x 512 (mt x nt16) 128-row tiles
#define WL2SZ 2048   // 8 experts x 256 (mt x nt8)

typedef unsigned short u16;
typedef unsigned long long u64;
typedef __attribute__((ext_vector_type(8))) short bf16x8;
typedef __attribute__((ext_vector_type(4))) float f32x4;

__device__ __forceinline__ u16 f2bf(float f) {
  __hip_bfloat16 h = __float2bfloat16(f);
  union { __hip_bfloat16 h; u16 u; } c; c.h = h; return c.u;
}

// fast GELU: 0.5x(1+erf(x/sqrt2)), erf via Abramowitz-Stegun 7.1.26 (|err|<=1.5e-7)
__device__ __forceinline__ float gelu_f(float v) {
  float z = fabsf(v) * 0.70710678118654752f;
  float t = __builtin_amdgcn_rcpf(1.0f + 0.3275911f * z);
  float poly = t * (0.254829592f +
               t * (-0.284496736f +
               t * (1.421413741f +
               t * (-1.453152027f +
               t * 1.061405429f))));
  float ez = __expf(-z * z);
  float erfz = 1.0f - poly * ez;
  erfz = copysignf(erfz, v);
  return 0.5f * v * (1.0f + erfz);
}

__device__ __forceinline__ void async_copy16(const void* g, void* l) {
  __builtin_amdgcn_global_load_lds(
      (const __attribute__((address_space(1))) unsigned int*)g,
      (__attribute__((address_space(3))) unsigned int*)l, 16, 0, 0);
}

// opaque LDS read (rule #18 discipline): ordering enforced by our asm waits
__device__ __forceinline__ bf16x8 ds_read16(const char* p) {
  bf16x8 r;
  asm volatile("ds_read_b128 %0, %1"
               : "=&v"(r)
               : "v"((const __attribute__((address_space(3))) char*)p));
  return r;
}

#define LGKM0()                                                                   \
  do {                                                                            \
    asm volatile("s_waitcnt lgkmcnt(0)" ::: "memory");                            \
    __builtin_amdgcn_sched_barrier(0);                                            \
  } while (0)
#define VMW0() asm volatile("s_waitcnt vmcnt(0)" ::: "memory")
#define BAR() asm volatile("s_barrier" ::: "memory")

// ===== K1: merged router (bid<4096) + weight transpose (bid>=4096) =====
__global__ __launch_bounds__(256) void prep_k(const float* __restrict__ x,
                                              const float* __restrict__ Wg,
                                              const float* __restrict__ W1,
                                              const float* __restrict__ W2,
                                              float* __restrict__ probs,
                                              float* __restrict__ probsT,
                                              u16* __restrict__ xb,
                                              u16* __restrict__ w1t,
                                              u16* __restrict__ w2t,
                                              u64* __restrict__ key,
                                              int* cnt, int* cnt2, int* gates) {
  __shared__ float tile[64][65];
  int bid = blockIdx.x, tid = threadIdx.x;
  if (bid < 4096) {
    // ---- router: fp64-accum logits + softmax; also zero key/cnt/gates ----
    if (tid < 4) key[bid * 4 + tid] = 0ull;
    if (bid == 0 && tid < NE) { cnt[tid] = 0; cnt2[tid] = 0; }
    if (bid == 0 && tid >= 8 && tid < 10) gates[tid - 8] = 0;
    int wid = tid >> 6, lane = tid & 63;
    int t = bid * 4 + wid;
    const float* xr = x + (size_t)t * DIM;
    u16* xbr = xb + (size_t)t * DIM;
    double acc[NE] = {0, 0, 0, 0, 0, 0, 0, 0};
#pragma unroll 1
    for (int it = 0; it < DIM / 64; ++it) {
      int d = it * 64 + lane;
      float xv = xr[d];
      xbr[d] = f2bf(xv);
      const float4* wrow = (const float4*)(Wg + (size_t)d * NE);
      float4 w0 = wrow[0], w1 = wrow[1];
      acc[0] += (double)xv * (double)w0.x;
      acc[1] += (double)xv * (double)w0.y;
      acc[2] += (double)xv * (double)w0.z;
      acc[3] += (double)xv * (double)w0.w;
      acc[4] += (double)xv * (double)w1.x;
      acc[5] += (double)xv * (double)w1.y;
      acc[6] += (double)xv * (double)w1.z;
      acc[7] += (double)xv * (double)w1.w;
    }
#pragma unroll
    for (int e = 0; e < NE; ++e)
      for (int o = 32; o > 0; o >>= 1) acc[e] += __shfl_down(acc[e], o, 64);
    if (lane == 0) {
      float l[NE], mx = -3.0e38f;
#pragma unroll
      for (int e = 0; e < NE; ++e) { l[e] = (float)acc[e]; mx = fmaxf(mx, l[e]); }
      float s = 0.f;
#pragma unroll
      for (int e = 0; e < NE; ++e) { l[e] = expf(l[e] - mx); s += l[e]; }
      float inv = 1.0f / s;
#pragma unroll
      for (int e = 0; e < NE; ++e) {
        float p = l[e] * inv;
        probs[(size_t)t * NE + e] = p;
        probsT[(size_t)e * T_TOK + t] = p;
      }
    }
  } else {
    // ---- weight transpose: fp32 [E][R][C] -> bf16 [E][C][R], 64x64 tiles ----
    int tz = bid - 4096;            // 0..8191
    int z = tz >> 9, bxy = tz & 511;
    const float* src;
    u16* dst;
    int R, C;
    if (z < 8) { src = W1 + (size_t)z * DIM * FF; dst = w1t + (size_t)z * DIM * FF; R = DIM; C = FF; }
    else       { src = W2 + (size_t)(z - 8) * FF * DIM; dst = w2t + (size_t)(z - 8) * FF * DIM; R = FF; C = DIM; }
    int nbx = C >> 6;
    int bx = bxy % nbx, by = bxy / nbx;
    int r0 = by * 64, c0 = bx * 64;
    int lr = tid >> 4, lc4 = (tid & 15) * 4;
#pragma unroll
    for (int p = 0; p < 4; ++p) {
      float4 v = *(const float4*)(src + (size_t)(r0 + p * 16 + lr) * C + c0 + lc4);
      tile[p * 16 + lr][lc4 + 0] = v.x;
      tile[p * 16 + lr][lc4 + 1] = v.y;
      tile[p * 16 + lr][lc4 + 2] = v.z;
      tile[p * 16 + lr][lc4 + 3] = v.w;
    }
    __syncthreads();
    int oc = tid >> 3, orr = (tid & 7) * 8;
#pragma unroll
    for (int p = 0; p < 2; ++p) {
      int c = p * 32 + oc;
      u16 h[8];
#pragma unroll
      for (int j = 0; j < 8; ++j) h[j] = f2bf(tile[orr + j][c]);
      *(uint4*)(dst + (size_t)(c0 + c) * R + r0 + orr) = *(uint4*)h;
    }
  }
}

// ===== K2: merged topk(8 blocks) + assign+slot (64 blocks, internal gate) =====
// 72 blocks, all co-resident -> spin-waits deadlock-free.
__global__ __launch_bounds__(256) void moe_route_k(const float* __restrict__ probsT,
                                                   const float* __restrict__ probs,
                                                   u64* __restrict__ key,
                                                   int* __restrict__ tok2exp,
                                                   float* __restrict__ wgt,
                                                   int* cnt, int* cnt2,
                                                   int* __restrict__ list,
                                                   int* basep, int* wl1, int* wl2,
                                                   int* gates) {
  __shared__ float pcol[T_TOK];          // 64 KB (topk blocks only)
  __shared__ unsigned whist[8][2048];    // 64 KB
  __shared__ unsigned hist[2048];
  __shared__ unsigned bcast[2];
  __shared__ unsigned wsum[4];
  __shared__ int wps[4];
  int bid = blockIdx.x, tid = threadIdx.x, wid = tid >> 6, lane = tid & 63;
  if (bid < 8) {
    // ---- topk: 3-level radix (11/11/10), per-wave L0 hist, shfl scans ----
    int e = bid;
    const float4* src4 = (const float4*)(probsT + (size_t)e * T_TOK);
    for (int i = tid; i < T_TOK / 4; i += 256) ((float4*)pcol)[i] = src4[i];
    for (int i = tid; i < 8 * 2048; i += 256) ((unsigned*)whist)[i] = 0;
    unsigned prefix = 0, remaining = CAPK;
#pragma unroll 1
    for (int lvl = 0; lvl < 3; ++lvl) {
      int nb = (lvl == 2) ? 1024 : 2048;
      if (lvl == 0) {
        __syncthreads();
        for (int i = tid; i < T_TOK; i += 256)
          atomicAdd(&whist[wid][__float_as_uint(pcol[i]) >> 21], 1u);
        __syncthreads();
        for (int j = tid; j < 2048; j += 256) {
          unsigned s2 = 0;
#pragma unroll
          for (int w = 0; w < 8; ++w) s2 += whist[w][j];
          hist[j] = s2;
        }
        __syncthreads();
      } else {
        for (int i = tid; i < 2048; i += 256) hist[i] = 0;
        __syncthreads();
        for (int i = tid; i < T_TOK; i += 256) {
          unsigned k = __float_as_uint(pcol[i]);
          bool m = (lvl == 1) ? ((k >> 21) == prefix) : ((k >> 10) == prefix);
          if (m) atomicAdd(&hist[(lvl == 1) ? ((k >> 10) & 2047u) : (k & 1023u)], 1u);
        }
        __syncthreads();
      }
      int nper = nb / 256;
      unsigned cv = 0;
      for (int j = 0; j < nper; ++j) cv += hist[tid * nper + j];
      unsigned s = cv;
#pragma unroll
      for (int o = 1; o < 64; o <<= 1) {
        unsigned tv = __shfl_down(s, o, 64);
        if (lane + o < 64) s += tv;
      }
      if (lane == 0) wsum[wid] = s;
      __syncthreads();
      unsigned above = 0;
      for (int w = wid + 1; w < 4; ++w) above += wsum[w];
      unsigned Sincl = s + above, Sexcl = Sincl - cv;
      if (Sincl >= remaining && Sexcl < remaining) {
        unsigned rem2 = remaining - Sexcl, cum2 = 0;
        for (int j = nper - 1; j >= 0; --j) {
          unsigned h = hist[tid * nper + j];
          if (cum2 + h >= rem2) { bcast[0] = (unsigned)(tid * nper + j); bcast[1] = rem2 - cum2; break; }
          cum2 += h;
        }
      }
      __syncthreads();
      unsigned b = bcast[0];
      remaining = bcast[1];
      prefix = (lvl == 0) ? b : (lvl == 1) ? ((prefix << 11) | b) : ((prefix << 10) | b);
      __syncthreads();
    }
    unsigned vk = prefix;
    int need = (int)remaining;
    const int CH = T_TOK / 256;
    int i0 = tid * CH;
    int myt = 0;
    for (int i = i0; i < i0 + CH; ++i)
      myt += (__float_as_uint(pcol[i]) == vk);
    int p = myt;
#pragma unroll
    for (int o = 1; o < 64; o <<= 1) {
      int tv = __shfl_up(p, o, 64);
      if (lane >= o) p += tv;
    }
    if (lane == 63) wps[wid] = p;
    __syncthreads();
    int wo = 0;
    for (int w = 0; w < wid; ++w) wo += wps[w];
    int run = wo + p - myt;
    u64 ebits = (u64)(7 - e);
    for (int i = i0; i < i0 + CH; ++i) {
      unsigned k = __float_as_uint(pcol[i]);
      bool sv = false;
      if (k > vk) sv = true;
      else if (k == vk) { if (run < need) sv = true; run++; }
      if (sv) atomicMax(&key[i], ((u64)k << 3) | ebits);
    }
    __threadfence();
    __syncthreads();
    if (tid == 0) atomicAdd(&gates[0], 1);
  } else {
    // ---- assign (wait topk) then slot/wl (internal arrival gate) ----
    if (tid == 0) {
      while (atomicAdd(&gates[0], 0) < 8) __builtin_amdgcn_s_sleep(8);
    }
    __syncthreads();
    __threadfence();
    int gid = (bid - 8) * 256 + tid;
    u64 k = key[gid];
    int best;
    float bp;
    if (k) {
      best = 7 - (int)(k & 7);
      bp = __uint_as_float((unsigned)(k >> 3));
    } else {
      best = 0; bp = -3.0e38f;
#pragma unroll
      for (int e = 0; e < NE; ++e) {
        float p = probs[(size_t)gid * NE + e];
        if (p > bp) { bp = p; best = e; }
      }
    }
    tok2exp[gid] = best;
    wgt[gid] = bp;
#pragma unroll
    for (int e = 0; e < NE; ++e) {
      u64 m = __ballot(best == e);
      if (best == e && lane == __ffsll(m) - 1) atomicAdd(&cnt[e], (int)__popcll(m));
    }
    __threadfence();
    __syncthreads();
    if (tid == 0) atomicAdd(&gates[1], 1);
    if (tid == 0) {
      while (atomicAdd(&gates[1], 0) < 64) __builtin_amdgcn_s_sleep(8);
    }
    __syncthreads();
    __threadfence();
    // slot compaction + basep + worklists
    int c[NE];
#pragma unroll
    for (int e = 0; e < NE; ++e) c[e] = cnt[e];
    if (gid < NE) {
      int r = 0;
      for (int e = 0; e < gid; ++e) r += c[e];
      basep[gid] = r;
    }
    if (gid < WL1SZ) {
      int e = gid & 7, j = gid >> 3;      // j 0..511
      int mte = (c[e] + 127) >> 7;
      wl1[gid] = (j < mte * 16) ? (e | ((j >> 4) << 4) | ((j & 15) << 12)) : -1;
    }
    if (gid >= WL1SZ && gid < WL1SZ + WL2SZ) {
      int g2 = gid - WL1SZ;
      int e = g2 & 7, j = g2 >> 3;        // j 0..255
      int mte = (c[e] + 127) >> 7;
      wl2[g2] = (j < mte * 8) ? (e | ((j >> 3) << 4) | ((j & 7) << 12)) : -1;
    }
    int te = tok2exp[gid];
    int bp_e = 0;
#pragma unroll
    for (int e = 0; e < NE; ++e) if (e < te) bp_e += c[e];
    int sl = 0;
#pragma unroll
    for (int e = 0; e < NE; ++e) {
      u64 m = __ballot(te == e);
      if (te == e) {
        int leader = __ffsll(m) - 1;
        int rank = __popcll(m & ((1ull << lane) - 1));
        int b = 0;
        if (lane == leader) b = atomicAdd(&cnt2[e], (int)__popcll(m));
        b = __shfl(b, leader, 64);
        sl = bp_e + b + rank;
      }
    }
    list[sl] = gid;
  }
}

// ===== FFN: m97-replica — 128x128 tile, BK=64, SINGLE 32KB buffer, 4 blocks/CU =====
// per tile: {stage -> vmcnt(0)+bar -> read/MFMA x2 -> bar}; cross-block wave
// rotation (m114) hides the drains. Swizzled LDS, asm ds_read, setprio,
// operand-swapped MFMA, XCD worklists.
// EPI=0: H[slot] = GELU(xb[tok] @ W1t^T)   (K=DIM, N=FF)
// EPI=1: out[tok] = wgt * (H[slot] @ W2t^T) (K=FF,  N=DIM)

#define MF(M, N_, AV, BV) acc[M][N_] = __builtin_amdgcn_mfma_f32_16x16x32_bf16(BV, AV, acc[M][N_], 0, 0, 0)

#define STG(kt)                                                                   \
  do {                                                                            \
    char* dA = sm;                                                                \
    char* dB = sm + 16384;                                                        \
    size_t ko = (size_t)(kt) * 128;                                               \
    async_copy16(aP0 + ko,      dA + tid * 16);                                   \
    async_copy16(aP1 + ko,      dA + 4096 + tid * 16);                            \
    async_copy16(aP0 + ko + 64, dA + 8192 + tid * 16);                            \
    async_copy16(aP1 + ko + 64, dA + 12288 + tid * 16);                           \
    async_copy16(bP0 + ko,      dB + tid * 16);                                   \
    async_copy16(bP1 + ko,      dB + 4096 + tid * 16);                            \
    async_copy16(bP0 + ko + 64, dB + 8192 + tid * 16);                            \
    async_copy16(bP1 + ko + 64, dB + 12288 + tid * 16);                           \
  } while (0)

#define DSRD(kkoff)                                                               \
  do {                                                                            \
    const char* pa = sm + (kkoff) + wr * 4096 + laneOff;                          \
    const char* pb = sm + 16384 + (kkoff) + wc * 4096 + laneOff;                  \
    a0 = ds_read16(pa);        a1 = ds_read16(pa + 1024);                         \
    a2 = ds_read16(pa + 2048); a3 = ds_read16(pa + 3072);                         \
    b0 = ds_read16(pb);        b1 = ds_read16(pb + 1024);                         \
    b2 = ds_read16(pb + 2048); b3 = ds_read16(pb + 3072);                         \
  } while (0)

#define MFMA16()                                                                  \
  do {                                                                            \
    __builtin_amdgcn_s_setprio(1);                                                \
    MF(0, 0, a0, b0); MF(0, 1, a0, b1); MF(0, 2, a0, b2); MF(0, 3, a0, b3);       \
    MF(1, 0, a1, b0); MF(1, 1, a1, b1); MF(1, 2, a1, b2); MF(1, 3, a1, b3);       \
    MF(2, 0, a2, b0); MF(2, 1, a2, b1); MF(2, 2, a2, b2); MF(2, 3, a2, b3);       \
    MF(3, 0, a3, b0); MF(3, 1, a3, b1); MF(3, 2, a3, b2); MF(3, 3, a3, b3);       \
    __builtin_amdgcn_s_setprio(0);                                                \
  } while (0)

template <int EPI>
__global__ __launch_bounds__(256, 4) void ffn_k(const u16* __restrict__ A,
                                                const u16* __restrict__ Bm,
                                                void* __restrict__ Out,
                                                const int* __restrict__ list,
                                                const float* __restrict__ wgt,
                                                const int* __restrict__ basep,
                                                const int* __restrict__ cnt,
                                                const int* __restrict__ wl) {
  constexpr int K = EPI ? FF : DIM;
  constexpr int N = EPI ? DIM : FF;
  constexpr int KT = K / 64;

  const int wle = wl[blockIdx.x];
  if (wle < 0) return;
  const int e = wle & 15, mt = (wle >> 4) & 255, nt = wle >> 12;
  const int ce = cnt[e];
  const int be = basep[e];

  __shared__ u16 smem[16384];   // 32 KiB single buffer: A 16KB + B 16KB
  __shared__ int toks[128];
  __shared__ float wsc[128];
  char* const sm = (char*)smem;

  const int tid = threadIdx.x;
  if (tid < 128) {
    int r = mt * 128 + tid;
    int tk = (r < ce) ? list[be + r] : list[be];
    toks[tid] = tk;
    if (EPI == 1) wsc[tid] = wgt[tk];
  }
  __syncthreads();

  const int wid = tid >> 6, lane = tid & 63;
  const int wr = wid >> 1, wc = wid & 1;
  (void)wid;
  // swizzled frag-read offset (2 rows per 128B line, XOR on line&3) — verified R4-R9
  const int laneOff = ((lane & 15) >> 1) * 128 + (lane & 1) * 64 +
                      (((lane >> 4) << 4) ^ ((((lane & 15) >> 1) & 3) << 4));

  // staging: thread covers rows r0 and r0+64; inverse-swizzled source column
  const int r0 = 2 * (tid >> 3) + ((tid & 7) >> 2);     // 0..63
  const int cbl = ((tid & 3) << 4) ^ (((tid >> 3) & 3) << 4);
  const char *aP0, *aP1;
  if (EPI == 0) {
    aP0 = (const char*)(A + (size_t)toks[r0] * K) + cbl;
    aP1 = (const char*)(A + (size_t)toks[r0 + 64] * K) + cbl;
  } else {
    aP0 = (const char*)(A + ((size_t)be + mt * 128 + r0) * K) + cbl;
    aP1 = (const char*)(A + ((size_t)be + mt * 128 + r0 + 64) * K) + cbl;
  }
  const char* bP0 = (const char*)(Bm + ((size_t)e * N + nt * 128 + r0) * K) + cbl;
  const char* bP1 = (const char*)(Bm + ((size_t)e * N + nt * 128 + r0 + 64) * K) + cbl;

  f32x4 acc[4][4];
#pragma unroll
  for (int m = 0; m < 4; ++m)
#pragma unroll
    for (int n = 0; n < 4; ++n) acc[m][n] = (f32x4){0.f, 0.f, 0.f, 0.f};

  bf16x8 a0, a1, a2, a3, b0, b1, b2, b3;

#pragma unroll 1
  for (int kt = 0; kt < KT; ++kt) {
    STG(kt);          // stage tile kt into the single buffer
    VMW0();
    BAR();            // tile visible to all waves
    DSRD(0);          // kk0 frags
    LGKM0();
    MFMA16();
    DSRD(8192);       // kk1 frags
    LGKM0();
    MFMA16();
    BAR();            // all reads done before next stage overwrites
  }

  // epilogue: operand-swap => acc reg index runs along output cols -> vector stores
  const int lc = lane & 15, lq = (lane >> 4) * 4;
#pragma unroll
  for (int m = 0; m < 4; ++m) {
    int trow = wr * 64 + m * 16 + lc;
    int grow = mt * 128 + trow;
    if (grow < ce) {
      if (EPI == 0) {
        size_t rowoff = (size_t)(be + grow) * FF + nt * 128 + wc * 64 + lq;
#pragma unroll
        for (int n = 0; n < 4; ++n) {
          ushort4 h4;
          h4.x = f2bf(gelu_f(acc[m][n][0]));
          h4.y = f2bf(gelu_f(acc[m][n][1]));
          h4.z = f2bf(gelu_f(acc[m][n][2]));
          h4.w = f2bf(gelu_f(acc[m][n][3]));
          *(ushort4*)((u16*)Out + rowoff + n * 16) = h4;
        }
      } else {
        float w = wsc[trow];
        size_t rowoff = (size_t)toks[trow] * DIM + nt * 128 + wc * 64 + lq;
#pragma unroll
        for (int n = 0; n < 4; ++n) {
          float4 o = make_float4(w * acc[m][n][0], w * acc[m][n][1],
                                 w * acc[m][n][2], w * acc[m][n][3]);
          *(float4*)((float*)Out + rowoff + n * 16) = o;
        }
      }
    }
  }
}

extern "C" void kernel_launch(void* const* d_in, const int* in_sizes, int n_in,
                              void* d_out, int out_size, void* d_ws, size_t ws_size,
                              hipStream_t stream) {
  (void)in_sizes; (void)n_in; (void)out_size; (void)ws_size;
  const float* x  = (const float*)d_in[0];
  const float* Wg = (const float*)d_in[1];
  const float* W1 = (const float*)d_in[2];
  const float* W2 = (const float*)d_in[3];
  float* out = (float*)d_out;

  char* ws = (char*)d_ws;
  size_t off = 0;
  auto alloc = [&](size_t bytes) -> void* {
    void* p = ws + off;
    off += (bytes + 255) & ~(size_t)255;
    return p;
  };
  u16* xb   = (u16*)alloc((size_t)T_TOK * DIM * 2);         // 32 MB
  u16* w1t  = (u16*)alloc((size_t)NE * FF * DIM * 2);       // 32 MB  [E][F][D]
  u16* w2t  = (u16*)alloc((size_t)NE * DIM * FF * 2);       // 32 MB  [E][D][F]
  u16* H    = (u16*)alloc((size_t)(T_TOK + 256) * FF * 2);  // 65 MB, padded
  float* probs  = (float*)alloc((size_t)T_TOK * NE * 4);
  float* probsT = (float*)alloc((size_t)NE * T_TOK * 4);
  u64* key      = (u64*)alloc((size_t)T_TOK * 8);
  float* wgt    = (float*)alloc((size_t)T_TOK * 4);
  int* tok2exp  = (int*)alloc((size_t)T_TOK * 4);
  int* list     = (int*)alloc((size_t)T_TOK * 4);
  int* cnt      = (int*)alloc(64);
  int* cnt2     = (int*)alloc(64);
  int* basep    = (int*)alloc(64);
  int* gates    = (int*)alloc(64);
  int* wl1      = (int*)alloc(WL1SZ * 4);
  int* wl2      = (int*)alloc(WL2SZ * 4);

  prep_k<<<4096 + 8192, 256, 0, stream>>>(x, Wg, W1, W2, probs, probsT, xb, w1t, w2t,
                                          key, cnt, cnt2, gates);
  moe_route_k<<<72, 256, 0, stream>>>(probsT, probs, key, tok2exp, wgt, cnt, cnt2,
                                      list, basep, wl1, wl2, gates);
  ffn_k<0><<<WL1SZ, 256, 0, stream>>>(xb, w1t, H, list, wgt, basep, cnt, wl1);
  ffn_k<1><<<WL2SZ, 256, 0, stream>>>(H, w2t, out, list, wgt, basep, cnt, wl2);
}